// Round 9
// baseline (296.724 us; speedup 1.0000x reference)
//
#include <hip/hip_runtime.h>
#include <math.h>

#define D 128
#define SXS 264   // fallback sX stride (u16)
#define SHS 132   // activation stride (u16): 66 dwords == 2 mod 8 -> conflict-free epi
#define SFS 132   // f32 out-buffer stride (dwords), fallback path

typedef unsigned int u32;
typedef unsigned short u16;
typedef __attribute__((ext_vector_type(8))) short bf16x8;
typedef __attribute__((ext_vector_type(4))) float f32x4;

__device__ __forceinline__ float bfl(u32 u) { return __uint_as_float(u << 16); }
__device__ __forceinline__ float bfh(u32 u) { return __uint_as_float(u & 0xFFFF0000u); }
__device__ __forceinline__ u16 f2bf(float f) {
    u32 u = __float_as_uint(f);
    return (u16)((u + 0x7FFFu + ((u >> 16) & 1u)) >> 16); // RNE (cold paths)
}
// HW packed f32->bf16 (RNE), 1 VALU op
__device__ __forceinline__ u32 cvt_pk_bf16(float lo, float hi) {
    u32 r;
    asm("v_cvt_pk_bf16_f32 %0, %1, %2" : "=v"(r) : "v"(lo), "v"(hi));
    return r;
}
__device__ __forceinline__ u16 cvt1_bf16(float v) { return (u16)cvt_pk_bf16(v, v); }
__device__ __forceinline__ float silu_f(float x) { return x / (1.0f + __expf(-x)); }

// ---------------- fused setup: weights->bf16T | coord remainder | zero aggf | zero cursor ----------------
__global__ __launch_bounds__(256) void setup_kernel(
    const float* __restrict__ We1, const float* __restrict__ We2,
    const float* __restrict__ Wn1, const float* __restrict__ Wn2,
    u16* __restrict__ wt,
    const float* __restrict__ coord, const float* __restrict__ lbox,
    float* __restrict__ coord_out, int n3,
    float* __restrict__ aggf, int nAgg4,
    int* __restrict__ cursor, int N,
    int B1, int B2, int B3)
{
    const int b = blockIdx.x, t = threadIdx.x;
    if (b < B1) {
        int i = b * 256 + t;
        if (i < 32768)        { int n = i >> 8, k = i & 255;              wt[i] = f2bf(We1[(size_t)k*D + n]); }
        else if (i < 49152)   { int j = i - 32768; int n = j >> 7, k = j & 127; wt[i] = f2bf(We2[(size_t)k*D + n]); }
        else if (i < 81920)   { int j = i - 49152; int n = j >> 8, k = j & 255; wt[i] = f2bf(Wn1[(size_t)k*D + n]); }
        else                  { int j = i - 81920; int n = j >> 7, k = j & 127; wt[i] = f2bf(Wn2[(size_t)k*D + n]); }
    } else if (b < B2) {
        int i = (b - B1) * 256 + t;
        if (i < n3) {
            float ld = lbox[i % 3];
            float c = coord[i];
            float r = fmodf(c, ld);
            if (r < 0.f) r += ld;
            coord_out[i] = r;
        }
    } else if (b < B3) {
        int i = (b - B2) * 256 + t;
        if (i < nAgg4) ((f32x4*)aggf)[i] = (f32x4){0.f, 0.f, 0.f, 0.f};
    } else {
        int i = (b - B3) * 256 + t;
        if (i < N) cursor[i] = 0;
    }
}

// ---------------- CSR build ----------------
__global__ void hist_kernel(const int* __restrict__ ei, int* __restrict__ cnt, int E) {
    int e = blockIdx.x * 256 + threadIdx.x;
    if (e < E) atomicAdd(&cnt[ei[e]], 1);
}

__global__ void scan1_kernel(const int* __restrict__ cnt, int* __restrict__ offs,
                             int* __restrict__ bsum, int n /* = N+1 */) {
    __shared__ int s[256];
    int t = threadIdx.x, b = blockIdx.x;
    int base = b * 1024 + t * 4;
    int v[4];
    #pragma unroll
    for (int i = 0; i < 4; ++i) { int idx = base + i; v[i] = (idx < n - 1) ? cnt[idx] : 0; }
    int lsum = v[0] + v[1] + v[2] + v[3];
    s[t] = lsum; __syncthreads();
    #pragma unroll
    for (int off = 1; off < 256; off <<= 1) {
        int x = (t >= off) ? s[t - off] : 0; __syncthreads();
        s[t] += x; __syncthreads();
    }
    int run = s[t] - lsum;
    #pragma unroll
    for (int i = 0; i < 4; ++i) { int idx = base + i; if (idx < n) offs[idx] = run; run += v[i]; }
    if (t == 255) bsum[b] = s[255];
}

__global__ void scan2_kernel(int* __restrict__ bsum, int nb) {
    __shared__ int s[64];
    int t = threadIdx.x;
    int orig = (t < nb) ? bsum[t] : 0;
    s[t] = orig; __syncthreads();
    #pragma unroll
    for (int off = 1; off < 64; off <<= 1) {
        int x = (t >= off) ? s[t - off] : 0; __syncthreads();
        s[t] += x; __syncthreads();
    }
    if (t < nb) bsum[t] = s[t] - orig;
}

__global__ void scan3_kernel(int* __restrict__ offs, const int* __restrict__ bsum,
                             int* __restrict__ cursor, int n) {
    int i = blockIdx.x * 256 + threadIdx.x;
    if (i < n) {
        int v = offs[i] + bsum[i >> 10];
        offs[i] = v;
        if (i < n - 1) cursor[i] = v;
    }
}

__global__ void scatter_kernel(const int* __restrict__ ei, int* __restrict__ cursor,
                               int* __restrict__ perm, int E) {
    int e = blockIdx.x * 256 + threadIdx.x;
    if (e < E) { int p = atomicAdd(&cursor[ei[e]], 1); perm[p] = e; }
}

// ---------------- P/Q precompute: P = h@W_top + be1, Q = h@W_mid (bf16) ----------------
__global__ __launch_bounds__(256, 4) void pq_kernel(
    const float* __restrict__ h, const u16* __restrict__ wt,
    const float* __restrict__ be1,
    u16* __restrict__ Pt, u16* __restrict__ Qt, int N)
{
    __shared__ __align__(16) u16 sA[64 * SHS];
    __shared__ __align__(16) u16 sO[64 * SHS];

    const int t = threadIdx.x;
    const int lane = t & 63;
    const int wid = t >> 6;
    const int n0 = blockIdx.x * 64;

    // stage h (f32 -> bf16) [64][128]
    {
        const int e = t & 63, q = t >> 6;
        int ng = n0 + e; int ns = (ng < N) ? ng : N - 1;
        const float4* src = (const float4*)(h + (size_t)ns * D + q * 32);
        u16* dst = sA + e * SHS + q * 32;
        #pragma unroll
        for (int c = 0; c < 4; ++c) {
            float4 a = src[2 * c], b = src[2 * c + 1];
            *(uint4*)(dst + c * 8) = make_uint4(cvt_pk_bf16(a.x, a.y), cvt_pk_bf16(a.z, a.w),
                                               cvt_pk_bf16(b.x, b.y), cvt_pk_bf16(b.z, b.w));
        }
    }
    __syncthreads();

    const int lrow = lane & 15;
    const int kg = lane >> 4;
    const int g4 = kg * 4;
    const int nbase = wid * 32;

    f32x4 accP[4][2] = {}, accQ[4][2] = {};
    {
        bf16x8 Bt[8], Bm[8];
        #pragma unroll
        for (int nn = 0; nn < 2; ++nn)
            #pragma unroll
            for (int s = 0; s < 4; ++s) {
                const u16* bp = wt + (size_t)(nbase + nn * 16 + lrow) * 256 + s * 32 + kg * 8;
                Bt[nn * 4 + s] = *(const bf16x8*)bp;
                Bm[nn * 4 + s] = *(const bf16x8*)(bp + 128);
            }
        #pragma unroll
        for (int s = 0; s < 4; ++s) {
            bf16x8 a[4];
            #pragma unroll
            for (int m = 0; m < 4; ++m)
                a[m] = *(const bf16x8*)(sA + (m * 16 + lrow) * SHS + s * 32 + kg * 8);
            #pragma unroll
            for (int m = 0; m < 4; ++m)
                #pragma unroll
                for (int nn = 0; nn < 2; ++nn) {
                    accP[m][nn] = __builtin_amdgcn_mfma_f32_16x16x32_bf16(a[m], Bt[nn * 4 + s], accP[m][nn], 0, 0, 0);
                    accQ[m][nn] = __builtin_amdgcn_mfma_f32_16x16x32_bf16(a[m], Bm[nn * 4 + s], accQ[m][nn], 0, 0, 0);
                }
        }
    }

    // --- P: +be1, pack bf16, coalesced copy-out ---
    #pragma unroll
    for (int nn = 0; nn < 2; ++nn) {
        int outc = nbase + nn * 16 + lrow;
        float bb = be1[outc];
        #pragma unroll
        for (int m = 0; m < 4; ++m)
            #pragma unroll
            for (int r = 0; r < 4; ++r)
                sO[(m * 16 + g4 + r) * SHS + outc] = cvt1_bf16(accP[m][nn][r] + bb);
    }
    __syncthreads();
    {
        const int f4 = t & 15, rb = t >> 4;
        #pragma unroll
        for (int p = 0; p < 4; ++p) {
            int row = rb + p * 16;
            int ng = n0 + row;
            if (ng < N)
                *(uint4*)(Pt + (size_t)ng * D + f4 * 8) = *(const uint4*)(sO + row * SHS + f4 * 8);
        }
    }
    __syncthreads();
    // --- Q ---
    #pragma unroll
    for (int nn = 0; nn < 2; ++nn) {
        int outc = nbase + nn * 16 + lrow;
        #pragma unroll
        for (int m = 0; m < 4; ++m)
            #pragma unroll
            for (int r = 0; r < 4; ++r)
                sO[(m * 16 + g4 + r) * SHS + outc] = cvt1_bf16(accQ[m][nn][r]);
    }
    __syncthreads();
    {
        const int f4 = t & 15, rb = t >> 4;
        #pragma unroll
        for (int p = 0; p < 4; ++p) {
            int row = rb + p * 16;
            int ng = n0 + row;
            if (ng < N)
                *(uint4*)(Qt + (size_t)ng * D + f4 * 8) = *(const uint4*)(sO + row * SHS + f4 * 8);
        }
    }
}

// ---------------- edge model (P/Q path; bf16 LDS union; 8 blocks/CU) ----------------
__global__ __launch_bounds__(256, 8) void edge_pq_kernel(
    const u16* __restrict__ Pt, const u16* __restrict__ Qt,
    const int* __restrict__ ei, const int* __restrict__ perm,
    const float* __restrict__ coord, const float* __restrict__ lbox,
    const u16* __restrict__ wt, const float* __restrict__ We1,
    const float* __restrict__ be2,
    float* __restrict__ ef_out, float* __restrict__ aggf, int E)
{
    __shared__ __align__(16) u16 uni[64 * SHS];   // 16896 B union: sH1 / sE16
    __shared__ int srow[64], scol[64], sEid[64];
    __shared__ float sRad[64];
    __shared__ float sW[128];
    u16* sH1 = uni;
    u16* sE16 = uni;

    const int t = threadIdx.x;
    const int lane = t & 63;
    const int wid = t >> 6;

    // bijective XCD swizzle (m204)
    int p0;
    {
        const int nwg = gridDim.x;
        const int orig = blockIdx.x;
        const int q = nwg >> 3, r = nwg & 7;
        const int xcd = orig & 7, idx = orig >> 3;
        const int tile = (xcd < r ? xcd * (q + 1) : r * (q + 1) + (xcd - r) * q) + idx;
        p0 = tile * 64;
    }

    if (t < 64) {
        int slot = p0 + t;
        int eg = __builtin_nontemporal_load(&perm[(slot < E) ? slot : (E - 1)]);
        sEid[t] = (p0 + t < E) ? eg : -1;
        int rr = __builtin_nontemporal_load(&ei[eg]);
        int cc = __builtin_nontemporal_load(&ei[(size_t)E + eg]);
        srow[t] = rr;
        scol[t] = cc;
        float rad = 0.f;
        #pragma unroll
        for (int d3 = 0; d3 < 3; ++d3) {
            float df = coord[(size_t)rr * 3 + d3] - coord[(size_t)cc * 3 + d3];
            float ld = lbox[d3];
            df = (df >  0.5f * ld) ? df - ld : df;
            df = (df < -0.5f * ld) ? df + ld : df;
            rad += df * df;
        }
        sRad[t] = rad;
    } else if (t < 192) {
        sW[t - 64] = We1[(size_t)256 * D + (t - 64)];   // radial row of We1
    }
    __syncthreads();

    // phase 1: gather P[row]+Q[col], + rad*w, SiLU -> sH1 bf16
    {
        const int e = t & 63, q = t >> 6;
        const u16* Pp = Pt + (size_t)srow[e] * D;
        const u16* Qp = Qt + (size_t)scol[e] * D;
        const float rad = sRad[e];
        #pragma unroll
        for (int c0 = 0; c0 < 4; ++c0) {
            int j0 = q * 32 + c0 * 8;
            uint4 pu = *(const uint4*)(Pp + j0);
            uint4 qu = *(const uint4*)(Qp + j0);
            u32 pa[4] = {pu.x, pu.y, pu.z, pu.w};
            u32 qa[4] = {qu.x, qu.y, qu.z, qu.w};
            u32 ow[4];
            #pragma unroll
            for (int k = 0; k < 4; ++k) {
                float w0 = sW[j0 + 2 * k], w1 = sW[j0 + 2 * k + 1];
                float v0 = silu_f(bfl(pa[k]) + bfl(qa[k]) + rad * w0);
                float v1 = silu_f(bfh(pa[k]) + bfh(qa[k]) + rad * w1);
                ow[k] = cvt_pk_bf16(v0, v1);
            }
            *(uint4*)(sH1 + e * SHS + j0) = make_uint4(ow[0], ow[1], ow[2], ow[3]);
        }
    }
    __syncthreads();

    const int lrow = lane & 15;
    const int kg = lane >> 4;
    const int g4 = kg * 4;
    const int nbase = wid * 32;

    // phase 2: GEMM2 (K=128)
    f32x4 acc2[4][2] = {};
    {
        bf16x8 B2[8];
        #pragma unroll
        for (int nn = 0; nn < 2; ++nn)
            #pragma unroll
            for (int s = 0; s < 4; ++s)
                B2[nn * 4 + s] = *(const bf16x8*)(wt + 32768 + (size_t)(nbase + nn * 16 + lrow) * 128 + s * 32 + kg * 8);
        #pragma unroll
        for (int s = 0; s < 4; ++s) {
            bf16x8 a[4];
            #pragma unroll
            for (int m = 0; m < 4; ++m)
                a[m] = *(const bf16x8*)(sH1 + (m * 16 + lrow) * SHS + s * 32 + kg * 8);
            #pragma unroll
            for (int m = 0; m < 4; ++m)
                #pragma unroll
                for (int nn = 0; nn < 2; ++nn)
                    acc2[m][nn] = __builtin_amdgcn_mfma_f32_16x16x32_bf16(a[m], B2[nn * 4 + s], acc2[m][nn], 0, 0, 0);
        }
    }
    __syncthreads();   // sH1 dead before sE16 overwrite

    // phase 3: bias + SiLU -> bf16 buffer (same union)
    #pragma unroll
    for (int nn = 0; nn < 2; ++nn) {
        int outc = nbase + nn * 16 + lrow;
        float bb = be2[outc];
        #pragma unroll
        for (int m = 0; m < 4; ++m)
            #pragma unroll
            for (int r = 0; r < 4; ++r)
                sE16[(m * 16 + g4 + r) * SHS + outc] = cvt1_bf16(silu_f(acc2[m][nn][r] + bb));
    }
    __syncthreads();

    // phase 4: merged ef write (NT) + segmented reduce into aggf
    {
        const int ct = t & 127;
        const int half = t >> 7;
        const int ebeg = half * 32, eend = ebeg + 32;
        float run = 0.f;
        int prev = srow[ebeg];
        for (int e = ebeg; e < eend; ++e) {
            int r = srow[e];
            if (r != prev) {
                if (run != 0.f) atomicAdd(&aggf[(size_t)prev * D + ct], run);
                run = 0.f; prev = r;
            }
            int eg = sEid[e];
            if (eg >= 0) {
                float v = __uint_as_float((u32)sE16[e * SHS + ct] << 16);
                __builtin_nontemporal_store(v, &ef_out[(size_t)eg * D + ct]);
                run += v;
            }
        }
        if (run != 0.f) atomicAdd(&aggf[(size_t)prev * D + ct], run);
    }
}

// ---------------- edge fallback (f32 staging, own GEMM1) ----------------
__global__ __launch_bounds__(256, 3) void edge_fb_kernel(
    const float* __restrict__ h,
    const int* __restrict__ ei, const int* __restrict__ perm,
    const float* __restrict__ coord, const float* __restrict__ lbox,
    const u16* __restrict__ wt,
    const float* __restrict__ We1, const float* __restrict__ be1,
    const float* __restrict__ be2,
    float* __restrict__ ef_out, float* __restrict__ aggf, int E)
{
    __shared__ __align__(16) u16 sX[64 * SXS];
    __shared__ __align__(16) u16 sH1[64 * SHS];
    __shared__ int srow[64], scol[64], sEid[64];
    __shared__ float sRad[64];

    const int t = threadIdx.x;
    const int lane = t & 63;
    const int wid = t >> 6;

    int p0;
    {
        const int nwg = gridDim.x;
        const int orig = blockIdx.x;
        const int q = nwg >> 3, r = nwg & 7;
        const int xcd = orig & 7, idx = orig >> 3;
        const int tile = (xcd < r ? xcd * (q + 1) : r * (q + 1) + (xcd - r) * q) + idx;
        p0 = tile * 64;
    }

    if (t < 64) {
        int slot = p0 + t;
        int eg = perm[(slot < E) ? slot : (E - 1)];
        sEid[t] = (p0 + t < E) ? eg : -1;
        srow[t] = ei[eg];
        scol[t] = ei[(size_t)E + eg];
    }
    __syncthreads();

    {
        const int e = t & 63;
        const int q = t >> 6;
        const int r = srow[e], c = scol[e];
        const float4* src = (const float4*)((q < 2) ? (h + (size_t)r * D + (q & 1) * 64)
                                                    : (h + (size_t)c * D + (q & 1) * 64));
        u16* dst = sX + e * SXS + q * 64;
        #pragma unroll
        for (int i = 0; i < 8; ++i) {
            float4 a = src[2 * i], b = src[2 * i + 1];
            *(uint4*)(dst + i * 8) = make_uint4(cvt_pk_bf16(a.x, a.y), cvt_pk_bf16(a.z, a.w),
                                               cvt_pk_bf16(b.x, b.y), cvt_pk_bf16(b.z, b.w));
        }
        if (t < 64) {
            int rr = srow[t], cc = scol[t];
            float rad = 0.f;
            #pragma unroll
            for (int d3 = 0; d3 < 3; ++d3) {
                float df = coord[(size_t)rr * 3 + d3] - coord[(size_t)cc * 3 + d3];
                float ld = lbox[d3];
                df = (df >  0.5f * ld) ? df - ld : df;
                df = (df < -0.5f * ld) ? df + ld : df;
                rad += df * df;
            }
            sRad[t] = rad;
        }
    }
    __syncthreads();

    const int lrow = lane & 15;
    const int kg = lane >> 4;
    const int g4 = kg * 4;
    const int nbase = wid * 32;

    f32x4 acc[4][2] = {};
    {
        bf16x8 B1[16];
        #pragma unroll
        for (int nn = 0; nn < 2; ++nn)
            #pragma unroll
            for (int s = 0; s < 8; ++s)
                B1[nn * 8 + s] = *(const bf16x8*)(wt + (size_t)(nbase + nn * 16 + lrow) * 256 + s * 32 + kg * 8);
        #pragma unroll
        for (int s = 0; s < 8; ++s) {
            bf16x8 a[4];
            #pragma unroll
            for (int m = 0; m < 4; ++m)
                a[m] = *(const bf16x8*)(sX + (m * 16 + lrow) * SXS + s * 32 + kg * 8);
            #pragma unroll
            for (int m = 0; m < 4; ++m)
                #pragma unroll
                for (int nn = 0; nn < 2; ++nn)
                    acc[m][nn] = __builtin_amdgcn_mfma_f32_16x16x32_bf16(a[m], B1[nn * 8 + s], acc[m][nn], 0, 0, 0);
        }
    }

    #pragma unroll
    for (int nn = 0; nn < 2; ++nn) {
        int outc = nbase + nn * 16 + lrow;
        float wl = We1[(size_t)256 * D + outc];
        float bb = be1[outc];
        #pragma unroll
        for (int m = 0; m < 4; ++m)
            #pragma unroll
            for (int r = 0; r < 4; ++r) {
                int e = m * 16 + g4 + r;
                float v = acc[m][nn][r] + sRad[e] * wl + bb;
                sH1[e * SHS + outc] = cvt1_bf16(silu_f(v));
            }
    }
    __syncthreads();

    f32x4 acc2[4][2] = {};
    {
        bf16x8 B2[8];
        #pragma unroll
        for (int nn = 0; nn < 2; ++nn)
            #pragma unroll
            for (int s = 0; s < 4; ++s)
                B2[nn * 4 + s] = *(const bf16x8*)(wt + 32768 + (size_t)(nbase + nn * 16 + lrow) * 128 + s * 32 + kg * 8);
        #pragma unroll
        for (int s = 0; s < 4; ++s) {
            bf16x8 a[4];
            #pragma unroll
            for (int m = 0; m < 4; ++m)
                a[m] = *(const bf16x8*)(sH1 + (m * 16 + lrow) * SHS + s * 32 + kg * 8);
            #pragma unroll
            for (int m = 0; m < 4; ++m)
                #pragma unroll
                for (int nn = 0; nn < 2; ++nn)
                    acc2[m][nn] = __builtin_amdgcn_mfma_f32_16x16x32_bf16(a[m], B2[nn * 4 + s], acc2[m][nn], 0, 0, 0);
        }
    }
    __syncthreads();

    float* sXf = (float*)sX;
    #pragma unroll
    for (int nn = 0; nn < 2; ++nn) {
        int outc = nbase + nn * 16 + lrow;
        float bb = be2[outc];
        #pragma unroll
        for (int m = 0; m < 4; ++m)
            #pragma unroll
            for (int r = 0; r < 4; ++r)
                sXf[(m * 16 + g4 + r) * SFS + outc] = silu_f(acc2[m][nn][r] + bb);
    }
    __syncthreads();

    {
        const int ct = t & 127;
        const int half = t >> 7;
        const int ebeg = half * 32, eend = ebeg + 32;
        float run = 0.f;
        int prev = srow[ebeg];
        for (int e = ebeg; e < eend; ++e) {
            int r = srow[e];
            if (r != prev) {
                if (run != 0.f) atomicAdd(&aggf[(size_t)prev * D + ct], run);
                run = 0.f; prev = r;
            }
            int eg = sEid[e];
            if (eg >= 0) {
                float v = sXf[e * SFS + ct];
                __builtin_nontemporal_store(v, &ef_out[(size_t)eg * D + ct]);
                run += v;
            }
        }
        if (run != 0.f) atomicAdd(&aggf[(size_t)prev * D + ct], run);
    }
}

// ---------------- node model (K-split single-buffer LDS, 6 blocks/CU) ----------------
__global__ __launch_bounds__(256, 6) void node_kernel(
    const float* __restrict__ h, const float* __restrict__ aggf,
    const u16* __restrict__ wt,
    const float* __restrict__ bn1, const float* __restrict__ bn2,
    float* __restrict__ h_out, int N)
{
    __shared__ __align__(16) u16 uni[64 * SHS];   // 16896 B union: sA(h) / sA(agg) / sH1 / sE16

    const int t = threadIdx.x;
    const int lane = t & 63;
    const int wid = t >> 6;
    const int n0 = blockIdx.x * 64;

    const int lrow = lane & 15;
    const int kg = lane >> 4;
    const int g4 = kg * 4;
    const int nbase = wid * 32;

    const int se = t & 63, sq = t >> 6;
    const int sng = n0 + se;
    const int sns = (sng < N) ? sng : N - 1;

    // phase 1a: stage h half [64][128]
    {
        const float4* src = (const float4*)(h + (size_t)sns * D + sq * 32);
        u16* dst = uni + se * SHS + sq * 32;
        #pragma unroll
        for (int c = 0; c < 4; ++c) {
            float4 a = src[2 * c], b = src[2 * c + 1];
            *(uint4*)(dst + c * 8) = make_uint4(cvt_pk_bf16(a.x, a.y), cvt_pk_bf16(a.z, a.w),
                                               cvt_pk_bf16(b.x, b.y), cvt_pk_bf16(b.z, b.w));
        }
    }
    __syncthreads();

    // phase 1b: GEMM1 first K=128 (h x Wn1t[:, 0:128])
    f32x4 acc[4][2] = {};
    {
        bf16x8 B1[8];
        #pragma unroll
        for (int nn = 0; nn < 2; ++nn)
            #pragma unroll
            for (int s = 0; s < 4; ++s)
                B1[nn * 4 + s] = *(const bf16x8*)(wt + 49152 + (size_t)(nbase + nn * 16 + lrow) * 256 + s * 32 + kg * 8);
        #pragma unroll
        for (int s = 0; s < 4; ++s) {
            bf16x8 a[4];
            #pragma unroll
            for (int m = 0; m < 4; ++m)
                a[m] = *(const bf16x8*)(uni + (m * 16 + lrow) * SHS + s * 32 + kg * 8);
            #pragma unroll
            for (int m = 0; m < 4; ++m)
                #pragma unroll
                for (int nn = 0; nn < 2; ++nn)
                    acc[m][nn] = __builtin_amdgcn_mfma_f32_16x16x32_bf16(a[m], B1[nn * 4 + s], acc[m][nn], 0, 0, 0);
        }
    }
    __syncthreads();   // all reads of h-tile done

    // phase 2a: stage agg half into same buffer
    {
        const float4* src = (const float4*)(aggf + (size_t)sns * D + sq * 32);
        u16* dst = uni + se * SHS + sq * 32;
        #pragma unroll
        for (int c = 0; c < 4; ++c) {
            float4 a = src[2 * c], b = src[2 * c + 1];
            *(uint4*)(dst + c * 8) = make_uint4(cvt_pk_bf16(a.x, a.y), cvt_pk_bf16(a.z, a.w),
                                               cvt_pk_bf16(b.x, b.y), cvt_pk_bf16(b.z, b.w));
        }
    }
    __syncthreads();

    // phase 2b: GEMM1 second K=128 (agg x Wn1t[:, 128:256]), accumulate
    {
        bf16x8 B1[8];
        #pragma unroll
        for (int nn = 0; nn < 2; ++nn)
            #pragma unroll
            for (int s = 0; s < 4; ++s)
                B1[nn * 4 + s] = *(const bf16x8*)(wt + 49152 + (size_t)(nbase + nn * 16 + lrow) * 256 + 128 + s * 32 + kg * 8);
        #pragma unroll
        for (int s = 0; s < 4; ++s) {
            bf16x8 a[4];
            #pragma unroll
            for (int m = 0; m < 4; ++m)
                a[m] = *(const bf16x8*)(uni + (m * 16 + lrow) * SHS + s * 32 + kg * 8);
            #pragma unroll
            for (int m = 0; m < 4; ++m)
                #pragma unroll
                for (int nn = 0; nn < 2; ++nn)
                    acc[m][nn] = __builtin_amdgcn_mfma_f32_16x16x32_bf16(a[m], B1[nn * 4 + s], acc[m][nn], 0, 0, 0);
        }
    }
    __syncthreads();   // agg-tile reads done before epi1 overwrite

    // phase 3: epi1 -> sH1 (bf16)
    #pragma unroll
    for (int nn = 0; nn < 2; ++nn) {
        int outc = nbase + nn * 16 + lrow;
        float bb = bn1[outc];
        #pragma unroll
        for (int m = 0; m < 4; ++m)
            #pragma unroll
            for (int r = 0; r < 4; ++r)
                uni[(m * 16 + g4 + r) * SHS + outc] = cvt1_bf16(silu_f(acc[m][nn][r] + bb));
    }
    __syncthreads();

    // phase 4: GEMM2 (K=128)
    f32x4 acc2[4][2] = {};
    {
        bf16x8 B2[8];
        #pragma unroll
        for (int nn = 0; nn < 2; ++nn)
            #pragma unroll
            for (int s = 0; s < 4; ++s)
                B2[nn * 4 + s] = *(const bf16x8*)(wt + 81920 + (size_t)(nbase + nn * 16 + lrow) * 128 + s * 32 + kg * 8);
        #pragma unroll
        for (int s = 0; s < 4; ++s) {
            bf16x8 a[4];
            #pragma unroll
            for (int m = 0; m < 4; ++m)
                a[m] = *(const bf16x8*)(uni + (m * 16 + lrow) * SHS + s * 32 + kg * 8);
            #pragma unroll
            for (int m = 0; m < 4; ++m)
                #pragma unroll
                for (int nn = 0; nn < 2; ++nn)
                    acc2[m][nn] = __builtin_amdgcn_mfma_f32_16x16x32_bf16(a[m], B2[nn * 4 + s], acc2[m][nn], 0, 0, 0);
        }
    }
    __syncthreads();   // sH1 dead before sE16 overwrite

    // phase 5: epi2 -> bf16 (residual added at write)
    #pragma unroll
    for (int nn = 0; nn < 2; ++nn) {
        int outc = nbase + nn * 16 + lrow;
        float bb = bn2[outc];
        #pragma unroll
        for (int m = 0; m < 4; ++m)
            #pragma unroll
            for (int r = 0; r < 4; ++r)
                uni[(m * 16 + g4 + r) * SHS + outc] = cvt1_bf16(acc2[m][nn][r] + bb);
    }
    __syncthreads();

    // phase 6: h_out = h + mlp_out (coalesced, NT)
    {
        const int f4 = t & 31;
        const int nb = t >> 5;
        #pragma unroll
        for (int i = 0; i < 8; ++i) {
            int nl = nb + i * 8;
            int ng = n0 + nl;
            if (ng < N) {
                const ushort4 mv = *(const ushort4*)(uni + nl * SHS + f4 * 4);
                const f32x4 hv = *(const f32x4*)&h[(size_t)ng * D + f4 * 4];
                f32x4 v;
                v[0] = hv[0] + __uint_as_float((u32)mv.x << 16);
                v[1] = hv[1] + __uint_as_float((u32)mv.y << 16);
                v[2] = hv[2] + __uint_as_float((u32)mv.z << 16);
                v[3] = hv[3] + __uint_as_float((u32)mv.w << 16);
                __builtin_nontemporal_store(v, (f32x4*)&h_out[(size_t)ng * D + f4 * 4]);
            }
        }
    }
}

extern "C" void kernel_launch(void* const* d_in, const int* in_sizes, int n_in,
                              void* d_out, int out_size, void* d_ws, size_t ws_size,
                              hipStream_t stream) {
    const float* h     = (const float*)d_in[0];
    const int*   ei    = (const int*)d_in[1];
    const float* coord = (const float*)d_in[2];
    const float* lbox  = (const float*)d_in[4];
    const float* We1   = (const float*)d_in[5];
    const float* be1   = (const float*)d_in[6];
    const float* We2   = (const float*)d_in[7];
    const float* be2   = (const float*)d_in[8];
    const float* Wn1   = (const float*)d_in[9];
    const float* bn1   = (const float*)d_in[10];
    const float* Wn2   = (const float*)d_in[11];
    const float* bn2   = (const float*)d_in[12];

    const int N = in_sizes[0] / D;
    const int E = in_sizes[1] / 2;

    float* out       = (float*)d_out;
    float* h_out     = out;                       // [N,128]
    float* coord_out = out + (size_t)N * D;       // [N,3]
    float* ef_out    = coord_out + (size_t)N * 3; // [E,128]
    float* aggf      = h_out;                     // f32 agg accumulator in-place

    // workspace layout
    int* wsi = (int*)d_ws;
    u16* wt     = (u16*)d_ws;                     // 98304 u16 = 49152 ints
    int* offs   = wsi + 49152;                    // N+1 (padded N+8)
    int* cursor = offs + (N + 8);                 // N   (padded N+8)
    int* bsum   = cursor + (N + 8);               // 64
    int* perm   = bsum + 64;                      // E
    u16* Pt     = (u16*)(perm + E);               // N*128 bf16
    u16* Qt     = Pt + (size_t)N * D;             // N*128 bf16

    size_t need = (size_t)((char*)(Qt + (size_t)N * D) - (char*)d_ws);
    const bool use_pq = ws_size >= need;

    const int nb1 = (N + 1 + 1023) / 1024;        // scan1 blocks (<=64)

    // fused setup: weights | coord | zero aggf | zero cursor
    const int n3 = N * 3;
    const int nAgg4 = N * D / 4;
    const int B1 = 384;
    const int B2 = B1 + (n3 + 255) / 256;
    const int B3 = B2 + (nAgg4 + 255) / 256;
    const int Bt = B3 + (N + 255) / 256;
    setup_kernel<<<Bt, 256, 0, stream>>>(We1, We2, Wn1, Wn2, wt,
                                         coord, lbox, coord_out, n3,
                                         aggf, nAgg4, cursor, N, B1, B2, B3);

    if (use_pq)
        pq_kernel<<<(N + 63) / 64, 256, 0, stream>>>(h, wt, be1, Pt, Qt, N);

    // CSR build
    hist_kernel<<<(E + 255) / 256, 256, 0, stream>>>(ei, cursor, E);
    scan1_kernel<<<nb1, 256, 0, stream>>>(cursor, offs, bsum, N + 1);
    scan2_kernel<<<1, 64, 0, stream>>>(bsum, nb1);
    scan3_kernel<<<(N + 1 + 255) / 256, 256, 0, stream>>>(offs, bsum, cursor, N + 1);
    scatter_kernel<<<(E + 255) / 256, 256, 0, stream>>>(ei, cursor, perm, E);

    if (use_pq)
        edge_pq_kernel<<<(E + 63) / 64, 256, 0, stream>>>(
            Pt, Qt, ei, perm, coord, lbox, wt, We1, be2, ef_out, aggf, E);
    else
        edge_fb_kernel<<<(E + 63) / 64, 256, 0, stream>>>(
            h, ei, perm, coord, lbox, wt, We1, be1, be2, ef_out, aggf, E);

    node_kernel<<<(N + 63) / 64, 256, 0, stream>>>(
        h, aggf, wt, bn1, bn2, h_out, N);
}

// Round 10
// 271.404 us; speedup vs baseline: 1.0933x; 1.0933x over previous
//
#include <hip/hip_runtime.h>
#include <math.h>

#define D 128
#define SXS 264   // node/fallback sX stride (u16)
#define SHS 132   // activation stride (u16): 66 dwords == 2 mod 8 -> conflict-free epi
#define SFS 132   // f32 out-buffer stride (dwords), fallback path

typedef unsigned int u32;
typedef unsigned short u16;
typedef __attribute__((ext_vector_type(8))) short bf16x8;
typedef __attribute__((ext_vector_type(4))) float f32x4;

__device__ __forceinline__ float bfl(u32 u) { return __uint_as_float(u << 16); }
__device__ __forceinline__ float bfh(u32 u) { return __uint_as_float(u & 0xFFFF0000u); }
__device__ __forceinline__ u16 f2bf(float f) {
    u32 u = __float_as_uint(f);
    return (u16)((u + 0x7FFFu + ((u >> 16) & 1u)) >> 16); // RNE (cold paths)
}
// HW packed f32->bf16 (RNE), 1 VALU op
__device__ __forceinline__ u32 cvt_pk_bf16(float lo, float hi) {
    u32 r;
    asm("v_cvt_pk_bf16_f32 %0, %1, %2" : "=v"(r) : "v"(lo), "v"(hi));
    return r;
}
__device__ __forceinline__ u16 cvt1_bf16(float v) { return (u16)cvt_pk_bf16(v, v); }
__device__ __forceinline__ float silu_f(float x) { return x / (1.0f + __expf(-x)); }

// ---------------- coord: out = remainder(coord, l) ----------------
__global__ void coord_kernel(const float* __restrict__ coord,
                             const float* __restrict__ lbox,
                             float* __restrict__ out, int n3) {
    int i = blockIdx.x * 256 + threadIdx.x;
    if (i < n3) {
        float ld = lbox[i % 3];
        float c = coord[i];
        float r = fmodf(c, ld);
        if (r < 0.f) r += ld;
        out[i] = r;
    }
}

// ---------------- weight prep: bf16 transposed Wt[n][k] into ws ----------------
__global__ void prep_weights(const float* __restrict__ We1, const float* __restrict__ We2,
                             const float* __restrict__ Wn1, const float* __restrict__ Wn2,
                             u16* __restrict__ wt) {
    int i = blockIdx.x * 256 + threadIdx.x;
    if (i < 32768)        { int n = i >> 8, k = i & 255;              wt[i] = f2bf(We1[(size_t)k*D + n]); }
    else if (i < 49152)   { int j = i - 32768; int n = j >> 7, k = j & 127; wt[i] = f2bf(We2[(size_t)k*D + n]); }
    else if (i < 81920)   { int j = i - 49152; int n = j >> 8, k = j & 255; wt[i] = f2bf(Wn1[(size_t)k*D + n]); }
    else if (i < 98304)   { int j = i - 81920; int n = j >> 7, k = j & 127; wt[i] = f2bf(Wn2[(size_t)k*D + n]); }
}

// ---------------- CSR build ----------------
__global__ void hist_kernel(const int* __restrict__ ei, int* __restrict__ cnt, int E) {
    int e = blockIdx.x * 256 + threadIdx.x;
    if (e < E) atomicAdd(&cnt[ei[e]], 1);
}

__global__ void scan1_kernel(const int* __restrict__ cnt, int* __restrict__ offs,
                             int* __restrict__ bsum, int n /* = N+1 */) {
    __shared__ int s[256];
    int t = threadIdx.x, b = blockIdx.x;
    int base = b * 1024 + t * 4;
    int v[4];
    #pragma unroll
    for (int i = 0; i < 4; ++i) { int idx = base + i; v[i] = (idx < n - 1) ? cnt[idx] : 0; }
    int lsum = v[0] + v[1] + v[2] + v[3];
    s[t] = lsum; __syncthreads();
    #pragma unroll
    for (int off = 1; off < 256; off <<= 1) {
        int x = (t >= off) ? s[t - off] : 0; __syncthreads();
        s[t] += x; __syncthreads();
    }
    int run = s[t] - lsum;
    #pragma unroll
    for (int i = 0; i < 4; ++i) { int idx = base + i; if (idx < n) offs[idx] = run; run += v[i]; }
    if (t == 255) bsum[b] = s[255];
}

__global__ void scan2_kernel(int* __restrict__ bsum, int nb) {
    __shared__ int s[64];
    int t = threadIdx.x;
    int orig = (t < nb) ? bsum[t] : 0;
    s[t] = orig; __syncthreads();
    #pragma unroll
    for (int off = 1; off < 64; off <<= 1) {
        int x = (t >= off) ? s[t - off] : 0; __syncthreads();
        s[t] += x; __syncthreads();
    }
    if (t < nb) bsum[t] = s[t] - orig;
}

__global__ void scan3_kernel(int* __restrict__ offs, const int* __restrict__ bsum,
                             int* __restrict__ cursor, int n) {
    int i = blockIdx.x * 256 + threadIdx.x;
    if (i < n) {
        int v = offs[i] + bsum[i >> 10];
        offs[i] = v;
        if (i < n - 1) cursor[i] = v;
    }
}

// writes either perm[p]=e (fallback) or edata[p]={e,row,col,0}
__global__ void scatter_kernel(const int* __restrict__ ei, int* __restrict__ cursor,
                               int* __restrict__ perm, int4* __restrict__ edata, int E) {
    int e = blockIdx.x * 256 + threadIdx.x;
    if (e < E) {
        int r = ei[e];
        int c = ei[(size_t)E + e];
        int p = atomicAdd(&cursor[r], 1);
        if (edata) edata[p] = make_int4(e, r, c, 0);
        else perm[p] = e;
    }
}

// ---------------- P/Q precompute: P = h@W_top + be1, Q = h@W_mid (bf16) ----------------
__global__ __launch_bounds__(256, 4) void pq_kernel(
    const float* __restrict__ h, const u16* __restrict__ wt,
    const float* __restrict__ be1,
    u16* __restrict__ Pt, u16* __restrict__ Qt,
    int* __restrict__ cursor, int N)
{
    __shared__ __align__(16) u16 sA[64 * SHS];
    __shared__ __align__(16) u16 sO[64 * SHS];

    const int t = threadIdx.x;
    const int lane = t & 63;
    const int wid = t >> 6;
    const int n0 = blockIdx.x * 64;

    // zero the CSR count array (replaces a fill dispatch)
    if (t < 64) { int zi = n0 + t; if (zi < N) cursor[zi] = 0; }

    // stage h (f32 -> bf16) [64][128]
    {
        const int e = t & 63, q = t >> 6;
        int ng = n0 + e; int ns = (ng < N) ? ng : N - 1;
        const float4* src = (const float4*)(h + (size_t)ns * D + q * 32);
        u16* dst = sA + e * SHS + q * 32;
        #pragma unroll
        for (int c = 0; c < 4; ++c) {
            float4 a = src[2 * c], b = src[2 * c + 1];
            *(uint4*)(dst + c * 8) = make_uint4(cvt_pk_bf16(a.x, a.y), cvt_pk_bf16(a.z, a.w),
                                               cvt_pk_bf16(b.x, b.y), cvt_pk_bf16(b.z, b.w));
        }
    }
    __syncthreads();

    const int lrow = lane & 15;
    const int kg = lane >> 4;
    const int g4 = kg * 4;
    const int nbase = wid * 32;

    f32x4 accP[4][2] = {}, accQ[4][2] = {};
    {
        bf16x8 Bt[8], Bm[8];
        #pragma unroll
        for (int nn = 0; nn < 2; ++nn)
            #pragma unroll
            for (int s = 0; s < 4; ++s) {
                const u16* bp = wt + (size_t)(nbase + nn * 16 + lrow) * 256 + s * 32 + kg * 8;
                Bt[nn * 4 + s] = *(const bf16x8*)bp;
                Bm[nn * 4 + s] = *(const bf16x8*)(bp + 128);
            }
        #pragma unroll
        for (int s = 0; s < 4; ++s) {
            bf16x8 a[4];
            #pragma unroll
            for (int m = 0; m < 4; ++m)
                a[m] = *(const bf16x8*)(sA + (m * 16 + lrow) * SHS + s * 32 + kg * 8);
            #pragma unroll
            for (int m = 0; m < 4; ++m)
                #pragma unroll
                for (int nn = 0; nn < 2; ++nn) {
                    accP[m][nn] = __builtin_amdgcn_mfma_f32_16x16x32_bf16(a[m], Bt[nn * 4 + s], accP[m][nn], 0, 0, 0);
                    accQ[m][nn] = __builtin_amdgcn_mfma_f32_16x16x32_bf16(a[m], Bm[nn * 4 + s], accQ[m][nn], 0, 0, 0);
                }
        }
    }

    // --- P: +be1, pack bf16, coalesced copy-out ---
    #pragma unroll
    for (int nn = 0; nn < 2; ++nn) {
        int outc = nbase + nn * 16 + lrow;
        float bb = be1[outc];
        #pragma unroll
        for (int m = 0; m < 4; ++m)
            #pragma unroll
            for (int r = 0; r < 4; ++r)
                sO[(m * 16 + g4 + r) * SHS + outc] = cvt1_bf16(accP[m][nn][r] + bb);
    }
    __syncthreads();
    {
        const int f4 = t & 15, rb = t >> 4;
        #pragma unroll
        for (int p = 0; p < 4; ++p) {
            int row = rb + p * 16;
            int ng = n0 + row;
            if (ng < N)
                *(uint4*)(Pt + (size_t)ng * D + f4 * 8) = *(const uint4*)(sO + row * SHS + f4 * 8);
        }
    }
    __syncthreads();
    // --- Q ---
    #pragma unroll
    for (int nn = 0; nn < 2; ++nn) {
        int outc = nbase + nn * 16 + lrow;
        #pragma unroll
        for (int m = 0; m < 4; ++m)
            #pragma unroll
            for (int r = 0; r < 4; ++r)
                sO[(m * 16 + g4 + r) * SHS + outc] = cvt1_bf16(accQ[m][nn][r]);
    }
    __syncthreads();
    {
        const int f4 = t & 15, rb = t >> 4;
        #pragma unroll
        for (int p = 0; p < 4; ++p) {
            int row = rb + p * 16;
            int ng = n0 + row;
            if (ng < N)
                *(uint4*)(Qt + (size_t)ng * D + f4 * 8) = *(const uint4*)(sO + row * SHS + f4 * 8);
        }
    }
}

// ---------------- edge model (P/Q path; bf16 LDS union; 8 blocks/CU) ----------------
__global__ __launch_bounds__(256, 8) void edge_pq_kernel(
    const u16* __restrict__ Pt, const u16* __restrict__ Qt,
    const int* __restrict__ ei, const int* __restrict__ perm,
    const int4* __restrict__ edata,
    const float* __restrict__ coord, const float* __restrict__ lbox,
    const u16* __restrict__ wt, const float* __restrict__ We1,
    const float* __restrict__ be2,
    float* __restrict__ ef_out, float* __restrict__ aggf, int E)
{
    __shared__ __align__(16) u16 uni[64 * SHS];   // 16896 B union: sH1 / sE16
    __shared__ int srow[64], scol[64], sEid[64];
    __shared__ float sRad[64];
    __shared__ float sW[128];
    u16* sH1 = uni;
    u16* sE16 = uni;

    const int t = threadIdx.x;
    const int lane = t & 63;
    const int wid = t >> 6;

    // bijective XCD swizzle (m204)
    int p0;
    {
        const int nwg = gridDim.x;
        const int orig = blockIdx.x;
        const int q = nwg >> 3, r = nwg & 7;
        const int xcd = orig & 7, idx = orig >> 3;
        const int tile = (xcd < r ? xcd * (q + 1) : r * (q + 1) + (xcd - r) * q) + idx;
        p0 = tile * 64;
    }

    if (t < 64) {
        int slot = p0 + t;
        bool valid = slot < E;
        int cs = valid ? slot : (E - 1);
        int eg, rr, cc;
        if (edata) {
            int4 ed = edata[cs];
            eg = ed.x; rr = ed.y; cc = ed.z;
        } else {
            eg = perm[cs];
            rr = ei[eg];
            cc = ei[(size_t)E + eg];
        }
        sEid[t] = valid ? eg : -1;
        srow[t] = rr;
        scol[t] = cc;
        float rad = 0.f;
        #pragma unroll
        for (int d3 = 0; d3 < 3; ++d3) {
            float df = coord[(size_t)rr * 3 + d3] - coord[(size_t)cc * 3 + d3];
            float ld = lbox[d3];
            df = (df >  0.5f * ld) ? df - ld : df;
            df = (df < -0.5f * ld) ? df + ld : df;
            rad += df * df;
        }
        sRad[t] = rad;
    } else if (t < 192) {
        sW[t - 64] = We1[(size_t)256 * D + (t - 64)];   // radial row of We1
    }
    __syncthreads();

    // phase 1: gather P[row]+Q[col], + rad*w, SiLU -> sH1 bf16
    {
        const int e = t & 63, q = t >> 6;
        const u16* Pp = Pt + (size_t)srow[e] * D;
        const u16* Qp = Qt + (size_t)scol[e] * D;
        const float rad = sRad[e];
        #pragma unroll
        for (int c0 = 0; c0 < 4; ++c0) {
            int j0 = q * 32 + c0 * 8;
            uint4 pu = *(const uint4*)(Pp + j0);
            uint4 qu = *(const uint4*)(Qp + j0);
            u32 pa[4] = {pu.x, pu.y, pu.z, pu.w};
            u32 qa[4] = {qu.x, qu.y, qu.z, qu.w};
            u32 ow[4];
            #pragma unroll
            for (int k = 0; k < 4; ++k) {
                float w0 = sW[j0 + 2 * k], w1 = sW[j0 + 2 * k + 1];
                float v0 = silu_f(bfl(pa[k]) + bfl(qa[k]) + rad * w0);
                float v1 = silu_f(bfh(pa[k]) + bfh(qa[k]) + rad * w1);
                ow[k] = cvt_pk_bf16(v0, v1);
            }
            *(uint4*)(sH1 + e * SHS + j0) = make_uint4(ow[0], ow[1], ow[2], ow[3]);
        }
    }
    __syncthreads();

    const int lrow = lane & 15;
    const int kg = lane >> 4;
    const int g4 = kg * 4;
    const int nbase = wid * 32;

    // phase 2: GEMM2 (K=128)
    f32x4 acc2[4][2] = {};
    {
        bf16x8 B2[8];
        #pragma unroll
        for (int nn = 0; nn < 2; ++nn)
            #pragma unroll
            for (int s = 0; s < 4; ++s)
                B2[nn * 4 + s] = *(const bf16x8*)(wt + 32768 + (size_t)(nbase + nn * 16 + lrow) * 128 + s * 32 + kg * 8);
        #pragma unroll
        for (int s = 0; s < 4; ++s) {
            bf16x8 a[4];
            #pragma unroll
            for (int m = 0; m < 4; ++m)
                a[m] = *(const bf16x8*)(sH1 + (m * 16 + lrow) * SHS + s * 32 + kg * 8);
            #pragma unroll
            for (int m = 0; m < 4; ++m)
                #pragma unroll
                for (int nn = 0; nn < 2; ++nn)
                    acc2[m][nn] = __builtin_amdgcn_mfma_f32_16x16x32_bf16(a[m], B2[nn * 4 + s], acc2[m][nn], 0, 0, 0);
        }
    }
    __syncthreads();   // sH1 dead before sE16 overwrite

    // phase 3: bias + SiLU -> bf16 buffer (same union)
    #pragma unroll
    for (int nn = 0; nn < 2; ++nn) {
        int outc = nbase + nn * 16 + lrow;
        float bb = be2[outc];
        #pragma unroll
        for (int m = 0; m < 4; ++m)
            #pragma unroll
            for (int r = 0; r < 4; ++r)
                sE16[(m * 16 + g4 + r) * SHS + outc] = cvt1_bf16(silu_f(acc2[m][nn][r] + bb));
    }
    __syncthreads();

    // phase 4: merged ef write (NT) + segmented reduce into aggf
    {
        const int ct = t & 127;
        const int half = t >> 7;
        const int ebeg = half * 32, eend = ebeg + 32;
        float run = 0.f;
        int prev = srow[ebeg];
        for (int e = ebeg; e < eend; ++e) {
            int r = srow[e];
            if (r != prev) {
                if (run != 0.f) atomicAdd(&aggf[(size_t)prev * D + ct], run);
                run = 0.f; prev = r;
            }
            int eg = sEid[e];
            if (eg >= 0) {
                float v = __uint_as_float((u32)sE16[e * SHS + ct] << 16);
                __builtin_nontemporal_store(v, &ef_out[(size_t)eg * D + ct]);
                run += v;
            }
        }
        if (run != 0.f) atomicAdd(&aggf[(size_t)prev * D + ct], run);
    }
}

// ---------------- edge fallback (f32 staging, own GEMM1) ----------------
__global__ __launch_bounds__(256, 3) void edge_fb_kernel(
    const float* __restrict__ h,
    const int* __restrict__ ei, const int* __restrict__ perm,
    const float* __restrict__ coord, const float* __restrict__ lbox,
    const u16* __restrict__ wt,
    const float* __restrict__ We1, const float* __restrict__ be1,
    const float* __restrict__ be2,
    float* __restrict__ ef_out, float* __restrict__ aggf, int E)
{
    __shared__ __align__(16) u16 sX[64 * SXS];
    __shared__ __align__(16) u16 sH1[64 * SHS];
    __shared__ int srow[64], scol[64], sEid[64];
    __shared__ float sRad[64];

    const int t = threadIdx.x;
    const int lane = t & 63;
    const int wid = t >> 6;

    int p0;
    {
        const int nwg = gridDim.x;
        const int orig = blockIdx.x;
        const int q = nwg >> 3, r = nwg & 7;
        const int xcd = orig & 7, idx = orig >> 3;
        const int tile = (xcd < r ? xcd * (q + 1) : r * (q + 1) + (xcd - r) * q) + idx;
        p0 = tile * 64;
    }

    if (t < 64) {
        int slot = p0 + t;
        int eg = perm[(slot < E) ? slot : (E - 1)];
        sEid[t] = (p0 + t < E) ? eg : -1;
        srow[t] = ei[eg];
        scol[t] = ei[(size_t)E + eg];
    }
    __syncthreads();

    {
        const int e = t & 63;
        const int q = t >> 6;
        const int r = srow[e], c = scol[e];
        const float4* src = (const float4*)((q < 2) ? (h + (size_t)r * D + (q & 1) * 64)
                                                    : (h + (size_t)c * D + (q & 1) * 64));
        u16* dst = sX + e * SXS + q * 64;
        #pragma unroll
        for (int i = 0; i < 8; ++i) {
            float4 a = src[2 * i], b = src[2 * i + 1];
            *(uint4*)(dst + i * 8) = make_uint4(cvt_pk_bf16(a.x, a.y), cvt_pk_bf16(a.z, a.w),
                                               cvt_pk_bf16(b.x, b.y), cvt_pk_bf16(b.z, b.w));
        }
        if (t < 64) {
            int rr = srow[t], cc = scol[t];
            float rad = 0.f;
            #pragma unroll
            for (int d3 = 0; d3 < 3; ++d3) {
                float df = coord[(size_t)rr * 3 + d3] - coord[(size_t)cc * 3 + d3];
                float ld = lbox[d3];
                df = (df >  0.5f * ld) ? df - ld : df;
                df = (df < -0.5f * ld) ? df + ld : df;
                rad += df * df;
            }
            sRad[t] = rad;
        }
    }
    __syncthreads();

    const int lrow = lane & 15;
    const int kg = lane >> 4;
    const int g4 = kg * 4;
    const int nbase = wid * 32;

    f32x4 acc[4][2] = {};
    {
        bf16x8 B1[16];
        #pragma unroll
        for (int nn = 0; nn < 2; ++nn)
            #pragma unroll
            for (int s = 0; s < 8; ++s)
                B1[nn * 8 + s] = *(const bf16x8*)(wt + (size_t)(nbase + nn * 16 + lrow) * 256 + s * 32 + kg * 8);
        #pragma unroll
        for (int s = 0; s < 8; ++s) {
            bf16x8 a[4];
            #pragma unroll
            for (int m = 0; m < 4; ++m)
                a[m] = *(const bf16x8*)(sX + (m * 16 + lrow) * SXS + s * 32 + kg * 8);
            #pragma unroll
            for (int m = 0; m < 4; ++m)
                #pragma unroll
                for (int nn = 0; nn < 2; ++nn)
                    acc[m][nn] = __builtin_amdgcn_mfma_f32_16x16x32_bf16(a[m], B1[nn * 8 + s], acc[m][nn], 0, 0, 0);
        }
    }

    #pragma unroll
    for (int nn = 0; nn < 2; ++nn) {
        int outc = nbase + nn * 16 + lrow;
        float wl = We1[(size_t)256 * D + outc];
        float bb = be1[outc];
        #pragma unroll
        for (int m = 0; m < 4; ++m)
            #pragma unroll
            for (int r = 0; r < 4; ++r) {
                int e = m * 16 + g4 + r;
                float v = acc[m][nn][r] + sRad[e] * wl + bb;
                sH1[e * SHS + outc] = cvt1_bf16(silu_f(v));
            }
    }
    __syncthreads();

    f32x4 acc2[4][2] = {};
    {
        bf16x8 B2[8];
        #pragma unroll
        for (int nn = 0; nn < 2; ++nn)
            #pragma unroll
            for (int s = 0; s < 4; ++s)
                B2[nn * 4 + s] = *(const bf16x8*)(wt + 32768 + (size_t)(nbase + nn * 16 + lrow) * 128 + s * 32 + kg * 8);
        #pragma unroll
        for (int s = 0; s < 4; ++s) {
            bf16x8 a[4];
            #pragma unroll
            for (int m = 0; m < 4; ++m)
                a[m] = *(const bf16x8*)(sH1 + (m * 16 + lrow) * SHS + s * 32 + kg * 8);
            #pragma unroll
            for (int m = 0; m < 4; ++m)
                #pragma unroll
                for (int nn = 0; nn < 2; ++nn)
                    acc2[m][nn] = __builtin_amdgcn_mfma_f32_16x16x32_bf16(a[m], B2[nn * 4 + s], acc2[m][nn], 0, 0, 0);
        }
    }
    __syncthreads();

    float* sXf = (float*)sX;
    #pragma unroll
    for (int nn = 0; nn < 2; ++nn) {
        int outc = nbase + nn * 16 + lrow;
        float bb = be2[outc];
        #pragma unroll
        for (int m = 0; m < 4; ++m)
            #pragma unroll
            for (int r = 0; r < 4; ++r)
                sXf[(m * 16 + g4 + r) * SFS + outc] = silu_f(acc2[m][nn][r] + bb);
    }
    __syncthreads();

    {
        const int ct = t & 127;
        const int half = t >> 7;
        const int ebeg = half * 32, eend = ebeg + 32;
        float run = 0.f;
        int prev = srow[ebeg];
        for (int e = ebeg; e < eend; ++e) {
            int r = srow[e];
            if (r != prev) {
                if (run != 0.f) atomicAdd(&aggf[(size_t)prev * D + ct], run);
                run = 0.f; prev = r;
            }
            int eg = sEid[e];
            if (eg >= 0) {
                float v = sXf[e * SFS + ct];
                __builtin_nontemporal_store(v, &ef_out[(size_t)eg * D + ct]);
                run += v;
            }
        }
        if (run != 0.f) atomicAdd(&aggf[(size_t)prev * D + ct], run);
    }
}

// ---------------- node model (aliased LDS, 4 blocks/CU) ----------------
__global__ __launch_bounds__(256, 4) void node_kernel(
    const float* __restrict__ h, const float* __restrict__ aggf,
    const u16* __restrict__ wt,
    const float* __restrict__ bn1, const float* __restrict__ bn2,
    float* __restrict__ h_out, int N)
{
    __shared__ __align__(16) u16 uni[64 * SXS];   // 33792 B union: sX / sH1 / sXf
    u16* sX = uni;
    u16* sH1 = uni;
    float* sXf = (float*)uni;

    const int t = threadIdx.x;
    const int lane = t & 63;
    const int wid = t >> 6;
    const int n0 = blockIdx.x * 64;

    {
        const int e = t & 63;
        const int q = t >> 6;
        int ng = n0 + e; int ns = (ng < N) ? ng : N - 1;
        const float4* src = (const float4*)(((q < 2) ? h : aggf) + (size_t)ns * D + (q & 1) * 64);
        u16* dst = sX + e * SXS + q * 64;
        #pragma unroll
        for (int i = 0; i < 8; ++i) {
            float4 a = src[2 * i], b = src[2 * i + 1];
            *(uint4*)(dst + i * 8) = make_uint4(cvt_pk_bf16(a.x, a.y), cvt_pk_bf16(a.z, a.w),
                                               cvt_pk_bf16(b.x, b.y), cvt_pk_bf16(b.z, b.w));
        }
    }
    __syncthreads();

    const int lrow = lane & 15;
    const int kg = lane >> 4;
    const int g4 = kg * 4;
    const int nbase = wid * 32;

    f32x4 acc[4][2] = {};
    {
        bf16x8 B1[16];
        #pragma unroll
        for (int nn = 0; nn < 2; ++nn)
            #pragma unroll
            for (int s = 0; s < 8; ++s)
                B1[nn * 8 + s] = *(const bf16x8*)(wt + 49152 + (size_t)(nbase + nn * 16 + lrow) * 256 + s * 32 + kg * 8);
        #pragma unroll
        for (int s = 0; s < 8; ++s) {
            bf16x8 a[4];
            #pragma unroll
            for (int m = 0; m < 4; ++m)
                a[m] = *(const bf16x8*)(sX + (m * 16 + lrow) * SXS + s * 32 + kg * 8);
            #pragma unroll
            for (int m = 0; m < 4; ++m)
                #pragma unroll
                for (int nn = 0; nn < 2; ++nn)
                    acc[m][nn] = __builtin_amdgcn_mfma_f32_16x16x32_bf16(a[m], B1[nn * 8 + s], acc[m][nn], 0, 0, 0);
        }
    }
    __syncthreads();   // sX dead before sH1 overwrite

    #pragma unroll
    for (int nn = 0; nn < 2; ++nn) {
        int outc = nbase + nn * 16 + lrow;
        float bb = bn1[outc];
        #pragma unroll
        for (int m = 0; m < 4; ++m)
            #pragma unroll
            for (int r = 0; r < 4; ++r)
                sH1[(m * 16 + g4 + r) * SHS + outc] = cvt1_bf16(silu_f(acc[m][nn][r] + bb));
    }
    __syncthreads();

    f32x4 acc2[4][2] = {};
    {
        bf16x8 B2[8];
        #pragma unroll
        for (int nn = 0; nn < 2; ++nn)
            #pragma unroll
            for (int s = 0; s < 4; ++s)
                B2[nn * 4 + s] = *(const bf16x8*)(wt + 81920 + (size_t)(nbase + nn * 16 + lrow) * 128 + s * 32 + kg * 8);
        #pragma unroll
        for (int s = 0; s < 4; ++s) {
            bf16x8 a[4];
            #pragma unroll
            for (int m = 0; m < 4; ++m)
                a[m] = *(const bf16x8*)(sH1 + (m * 16 + lrow) * SHS + s * 32 + kg * 8);
            #pragma unroll
            for (int m = 0; m < 4; ++m)
                #pragma unroll
                for (int nn = 0; nn < 2; ++nn)
                    acc2[m][nn] = __builtin_amdgcn_mfma_f32_16x16x32_bf16(a[m], B2[nn * 4 + s], acc2[m][nn], 0, 0, 0);
        }
    }
    __syncthreads();   // sH1 dead before sXf overwrite

    #pragma unroll
    for (int nn = 0; nn < 2; ++nn) {
        int outc = nbase + nn * 16 + lrow;
        float bb = bn2[outc];
        #pragma unroll
        for (int m = 0; m < 4; ++m)
            #pragma unroll
            for (int r = 0; r < 4; ++r)
                sXf[(m * 16 + g4 + r) * SFS + outc] = acc2[m][nn][r] + bb;
    }
    __syncthreads();

    {
        const int f4 = t & 31;
        const int nb = t >> 5;
        #pragma unroll
        for (int i = 0; i < 8; ++i) {
            int nl = nb + i * 8;
            int ng = n0 + nl;
            if (ng < N) {
                f32x4 v = *(const f32x4*)&sXf[nl * SFS + f4 * 4];
                const f32x4 hv = *(const f32x4*)&h[(size_t)ng * D + f4 * 4];
                v += hv;
                __builtin_nontemporal_store(v, (f32x4*)&h_out[(size_t)ng * D + f4 * 4]);
            }
        }
    }
}

extern "C" void kernel_launch(void* const* d_in, const int* in_sizes, int n_in,
                              void* d_out, int out_size, void* d_ws, size_t ws_size,
                              hipStream_t stream) {
    const float* h     = (const float*)d_in[0];
    const int*   ei    = (const int*)d_in[1];
    const float* coord = (const float*)d_in[2];
    const float* lbox  = (const float*)d_in[4];
    const float* We1   = (const float*)d_in[5];
    const float* be1   = (const float*)d_in[6];
    const float* We2   = (const float*)d_in[7];
    const float* be2   = (const float*)d_in[8];
    const float* Wn1   = (const float*)d_in[9];
    const float* bn1   = (const float*)d_in[10];
    const float* Wn2   = (const float*)d_in[11];
    const float* bn2   = (const float*)d_in[12];

    const int N = in_sizes[0] / D;
    const int E = in_sizes[1] / 2;

    float* out       = (float*)d_out;
    float* h_out     = out;                       // [N,128]
    float* coord_out = out + (size_t)N * D;       // [N,3]
    float* ef_out    = coord_out + (size_t)N * 3; // [E,128]
    float* aggf      = h_out;                     // f32 agg accumulator in-place

    // workspace layout: wt | offs | cursor | bsum | perm | Pt | Qt | edata
    int* wsi = (int*)d_ws;
    u16* wt     = (u16*)d_ws;                     // 98304 u16 = 49152 ints
    int* offs   = wsi + 49152;                    // N+1 (padded N+8)
    int* cursor = offs + (N + 8);                 // N   (padded N+8)
    int* bsum   = cursor + (N + 8);               // 64
    int* perm   = bsum + 64;                      // E
    u16* Pt     = (u16*)(perm + E);               // N*128 bf16
    u16* Qt     = Pt + (size_t)N * D;             // N*128 bf16
    int4* edata = (int4*)(((uintptr_t)(Qt + (size_t)N * D) + 15) & ~(uintptr_t)15); // E int4

    size_t need_pq = (size_t)((char*)(Qt + (size_t)N * D) - (char*)d_ws);
    size_t need_ed = (size_t)((char*)(edata + E) - (char*)d_ws);
    const bool use_pq = ws_size >= need_pq;
    const bool use_ed = use_pq && ws_size >= need_ed;
    int4* edp = use_ed ? edata : nullptr;

    const int nb1 = (N + 1 + 1023) / 1024;        // scan1 blocks (<=64)

    prep_weights<<<384, 256, 0, stream>>>(We1, We2, Wn1, Wn2, wt);
    if (use_pq)
        pq_kernel<<<(N + 63) / 64, 256, 0, stream>>>(h, wt, be1, Pt, Qt, cursor, N);
    else
        hipMemsetAsync(cursor, 0, (size_t)N * sizeof(int), stream);
    coord_kernel<<<(N * 3 + 255) / 256, 256, 0, stream>>>(coord, lbox, coord_out, N * 3);

    // zero agg accumulator (h_out region)
    hipMemsetAsync(aggf, 0, (size_t)N * D * sizeof(float), stream);

    // CSR build
    hist_kernel<<<(E + 255) / 256, 256, 0, stream>>>(ei, cursor, E);
    scan1_kernel<<<nb1, 256, 0, stream>>>(cursor, offs, bsum, N + 1);
    scan2_kernel<<<1, 64, 0, stream>>>(bsum, nb1);
    scan3_kernel<<<(N + 1 + 255) / 256, 256, 0, stream>>>(offs, bsum, cursor, N + 1);
    scatter_kernel<<<(E + 255) / 256, 256, 0, stream>>>(ei, cursor, perm, edp, E);

    if (use_pq)
        edge_pq_kernel<<<(E + 63) / 64, 256, 0, stream>>>(
            Pt, Qt, ei, perm, edp, coord, lbox, wt, We1, be2, ef_out, aggf, E);
    else
        edge_fb_kernel<<<(E + 63) / 64, 256, 0, stream>>>(
            h, ei, perm, coord, lbox, wt, We1, be1, be2, ef_out, aggf, E);

    node_kernel<<<(N + 63) / 64, 256, 0, stream>>>(
        h, aggf, wt, bn1, bn2, h_out, N);
}

// Round 12
// 249.725 us; speedup vs baseline: 1.1882x; 1.0868x over previous
//
#include <hip/hip_runtime.h>
#include <math.h>

#define D 128
#define SXS 264   // node/fallback sX stride (u16)
#define SHS 132   // activation stride (u16): 66 dwords == 2 mod 8 -> conflict-free epi
#define SFS 132   // f32 out-buffer stride (dwords), fallback path

typedef unsigned int u32;
typedef unsigned short u16;
typedef __attribute__((ext_vector_type(8))) short bf16x8;
typedef __attribute__((ext_vector_type(4))) float f32x4;
typedef __attribute__((ext_vector_type(2))) float f32x2;

__device__ __forceinline__ float bfl(u32 u) { return __uint_as_float(u << 16); }
__device__ __forceinline__ float bfh(u32 u) { return __uint_as_float(u & 0xFFFF0000u); }
__device__ __forceinline__ u16 f2bf(float f) {
    u32 u = __float_as_uint(f);
    return (u16)((u + 0x7FFFu + ((u >> 16) & 1u)) >> 16); // RNE (cold paths)
}
// HW packed f32->bf16 (RNE), 1 VALU op
__device__ __forceinline__ u32 cvt_pk_bf16(float lo, float hi) {
    u32 r;
    asm("v_cvt_pk_bf16_f32 %0, %1, %2" : "=v"(r) : "v"(lo), "v"(hi));
    return r;
}
__device__ __forceinline__ u16 cvt1_bf16(float v) { return (u16)cvt_pk_bf16(v, v); }
__device__ __forceinline__ float silu_f(float x) { return x / (1.0f + __expf(-x)); }
// device-scope packed bf16 atomic add (gfx940+), no return
__device__ __forceinline__ void atomic_pk_add_bf16(u16* addr, u32 pk) {
    asm volatile("global_atomic_pk_add_bf16 %0, %1, off sc1"
                 :: "v"(addr), "v"(pk) : "memory");
}

// ---------------- coord: out = remainder(coord, l) (standalone, fallback path) ----------------
__global__ void coord_kernel(const float* __restrict__ coord,
                             const float* __restrict__ lbox,
                             float* __restrict__ out, int n3) {
    int i = blockIdx.x * 256 + threadIdx.x;
    if (i < n3) {
        float ld = lbox[i % 3];
        float c = coord[i];
        float r = fmodf(c, ld);
        if (r < 0.f) r += ld;
        out[i] = r;
    }
}

// ---------------- weight prep: bf16 transposed Wt[n][k] into ws ----------------
__global__ void prep_weights(const float* __restrict__ We1, const float* __restrict__ We2,
                             const float* __restrict__ Wn1, const float* __restrict__ Wn2,
                             u16* __restrict__ wt) {
    int i = blockIdx.x * 256 + threadIdx.x;
    if (i < 32768)        { int n = i >> 8, k = i & 255;              wt[i] = f2bf(We1[(size_t)k*D + n]); }
    else if (i < 49152)   { int j = i - 32768; int n = j >> 7, k = j & 127; wt[i] = f2bf(We2[(size_t)k*D + n]); }
    else if (i < 81920)   { int j = i - 49152; int n = j >> 8, k = j & 255; wt[i] = f2bf(Wn1[(size_t)k*D + n]); }
    else if (i < 98304)   { int j = i - 81920; int n = j >> 7, k = j & 127; wt[i] = f2bf(Wn2[(size_t)k*D + n]); }
}

// ---------------- CSR build ----------------
__global__ void hist_kernel(const int* __restrict__ ei, int* __restrict__ cnt, int E) {
    int e = blockIdx.x * 256 + threadIdx.x;
    if (e < E) atomicAdd(&cnt[ei[e]], 1);
}

__global__ void scan1_kernel(const int* __restrict__ cnt, int* __restrict__ offs,
                             int* __restrict__ bsum, int n /* = N+1 */) {
    __shared__ int s[256];
    int t = threadIdx.x, b = blockIdx.x;
    int base = b * 1024 + t * 4;
    int v[4];
    #pragma unroll
    for (int i = 0; i < 4; ++i) { int idx = base + i; v[i] = (idx < n - 1) ? cnt[idx] : 0; }
    int lsum = v[0] + v[1] + v[2] + v[3];
    s[t] = lsum; __syncthreads();
    #pragma unroll
    for (int off = 1; off < 256; off <<= 1) {
        int x = (t >= off) ? s[t - off] : 0; __syncthreads();
        s[t] += x; __syncthreads();
    }
    int run = s[t] - lsum;
    #pragma unroll
    for (int i = 0; i < 4; ++i) { int idx = base + i; if (idx < n) offs[idx] = run; run += v[i]; }
    if (t == 255) bsum[b] = s[255];
}

__global__ void scan2_kernel(int* __restrict__ bsum, int nb) {
    __shared__ int s[64];
    int t = threadIdx.x;
    int orig = (t < nb) ? bsum[t] : 0;
    s[t] = orig; __syncthreads();
    #pragma unroll
    for (int off = 1; off < 64; off <<= 1) {
        int x = (t >= off) ? s[t - off] : 0; __syncthreads();
        s[t] += x; __syncthreads();
    }
    if (t < nb) bsum[t] = s[t] - orig;
}

__global__ void scan3_kernel(int* __restrict__ offs, const int* __restrict__ bsum,
                             int* __restrict__ cursor, int n) {
    int i = blockIdx.x * 256 + threadIdx.x;
    if (i < n) {
        int v = offs[i] + bsum[i >> 10];
        offs[i] = v;
        if (i < n - 1) cursor[i] = v;
    }
}

// writes either perm[p]=e (fallback) or edata[p]={e,row,col,0}
__global__ void scatter_kernel(const int* __restrict__ ei, int* __restrict__ cursor,
                               int* __restrict__ perm, int4* __restrict__ edata, int E) {
    int e = blockIdx.x * 256 + threadIdx.x;
    if (e < E) {
        int r = ei[e];
        int c = ei[(size_t)E + e];
        int p = atomicAdd(&cursor[r], 1);
        if (edata) edata[p] = make_int4(e, r, c, 0);
        else perm[p] = e;
    }
}

// ---------------- P/Q precompute (+ coord tail blocks): P = h@W_top + be1, Q = h@W_mid ----------------
__global__ __launch_bounds__(256, 4) void pq_kernel(
    const float* __restrict__ h, const u16* __restrict__ wt,
    const float* __restrict__ be1,
    u16* __restrict__ Pt, u16* __restrict__ Qt,
    int* __restrict__ cursor, int N,
    const float* __restrict__ coord, const float* __restrict__ lbox,
    float* __restrict__ coord_out, int n3, int NBn)
{
    __shared__ __align__(16) u16 sA[64 * SHS];
    __shared__ __align__(16) u16 sO[64 * SHS];

    const int t = threadIdx.x;

    // tail blocks: coord remainder
    if (blockIdx.x >= NBn) {
        int i = (blockIdx.x - NBn) * 256 + t;
        if (i < n3) {
            float ld = lbox[i % 3];
            float c = coord[i];
            float r = fmodf(c, ld);
            if (r < 0.f) r += ld;
            coord_out[i] = r;
        }
        return;
    }

    const int lane = t & 63;
    const int wid = t >> 6;
    const int n0 = blockIdx.x * 64;

    // zero the CSR count array (replaces a fill dispatch)
    if (t < 64) { int zi = n0 + t; if (zi < N) cursor[zi] = 0; }

    // stage h (f32 -> bf16) [64][128]
    {
        const int e = t & 63, q = t >> 6;
        int ng = n0 + e; int ns = (ng < N) ? ng : N - 1;
        const float4* src = (const float4*)(h + (size_t)ns * D + q * 32);
        u16* dst = sA + e * SHS + q * 32;
        #pragma unroll
        for (int c = 0; c < 4; ++c) {
            float4 a = src[2 * c], b = src[2 * c + 1];
            *(uint4*)(dst + c * 8) = make_uint4(cvt_pk_bf16(a.x, a.y), cvt_pk_bf16(a.z, a.w),
                                               cvt_pk_bf16(b.x, b.y), cvt_pk_bf16(b.z, b.w));
        }
    }
    __syncthreads();

    const int lrow = lane & 15;
    const int kg = lane >> 4;
    const int g4 = kg * 4;
    const int nbase = wid * 32;

    f32x4 accP[4][2] = {}, accQ[4][2] = {};
    {
        bf16x8 Bt[8], Bm[8];
        #pragma unroll
        for (int nn = 0; nn < 2; ++nn)
            #pragma unroll
            for (int s = 0; s < 4; ++s) {
                const u16* bp = wt + (size_t)(nbase + nn * 16 + lrow) * 256 + s * 32 + kg * 8;
                Bt[nn * 4 + s] = *(const bf16x8*)bp;
                Bm[nn * 4 + s] = *(const bf16x8*)(bp + 128);
            }
        #pragma unroll
        for (int s = 0; s < 4; ++s) {
            bf16x8 a[4];
            #pragma unroll
            for (int m = 0; m < 4; ++m)
                a[m] = *(const bf16x8*)(sA + (m * 16 + lrow) * SHS + s * 32 + kg * 8);
            #pragma unroll
            for (int m = 0; m < 4; ++m)
                #pragma unroll
                for (int nn = 0; nn < 2; ++nn) {
                    accP[m][nn] = __builtin_amdgcn_mfma_f32_16x16x32_bf16(a[m], Bt[nn * 4 + s], accP[m][nn], 0, 0, 0);
                    accQ[m][nn] = __builtin_amdgcn_mfma_f32_16x16x32_bf16(a[m], Bm[nn * 4 + s], accQ[m][nn], 0, 0, 0);
                }
        }
    }

    // --- P: +be1, pack bf16, coalesced copy-out ---
    #pragma unroll
    for (int nn = 0; nn < 2; ++nn) {
        int outc = nbase + nn * 16 + lrow;
        float bb = be1[outc];
        #pragma unroll
        for (int m = 0; m < 4; ++m)
            #pragma unroll
            for (int r = 0; r < 4; ++r)
                sO[(m * 16 + g4 + r) * SHS + outc] = cvt1_bf16(accP[m][nn][r] + bb);
    }
    __syncthreads();
    {
        const int f4 = t & 15, rb = t >> 4;
        #pragma unroll
        for (int p = 0; p < 4; ++p) {
            int row = rb + p * 16;
            int ng = n0 + row;
            if (ng < N)
                *(uint4*)(Pt + (size_t)ng * D + f4 * 8) = *(const uint4*)(sO + row * SHS + f4 * 8);
        }
    }
    __syncthreads();
    // --- Q ---
    #pragma unroll
    for (int nn = 0; nn < 2; ++nn) {
        int outc = nbase + nn * 16 + lrow;
        #pragma unroll
        for (int m = 0; m < 4; ++m)
            #pragma unroll
            for (int r = 0; r < 4; ++r)
                sO[(m * 16 + g4 + r) * SHS + outc] = cvt1_bf16(accQ[m][nn][r]);
    }
    __syncthreads();
    {
        const int f4 = t & 15, rb = t >> 4;
        #pragma unroll
        for (int p = 0; p < 4; ++p) {
            int row = rb + p * 16;
            int ng = n0 + row;
            if (ng < N)
                *(uint4*)(Qt + (size_t)ng * D + f4 * 8) = *(const uint4*)(sO + row * SHS + f4 * 8);
        }
    }
}

// ---------------- edge model (P/Q path; bf16 LDS union; 8 blocks/CU) ----------------
__global__ __launch_bounds__(256, 8) void edge_pq_kernel(
    const u16* __restrict__ Pt, const u16* __restrict__ Qt,
    const int* __restrict__ ei, const int* __restrict__ perm,
    const int4* __restrict__ edata,
    const float* __restrict__ coord, const float* __restrict__ lbox,
    const u16* __restrict__ wt, const float* __restrict__ We1,
    const float* __restrict__ be2,
    float* __restrict__ ef_out, float* __restrict__ aggf,
    u16* __restrict__ agg16, int E)
{
    __shared__ __align__(16) u16 uni[64 * SHS];   // 16896 B union: sH1 / sE16
    __shared__ int srow[64], scol[64], sEid[64];
    __shared__ float sRad[64];
    __shared__ float sW[128];
    u16* sH1 = uni;
    u16* sE16 = uni;

    const int t = threadIdx.x;
    const int lane = t & 63;
    const int wid = t >> 6;

    // bijective XCD swizzle (m204)
    int p0;
    {
        const int nwg = gridDim.x;
        const int orig = blockIdx.x;
        const int q = nwg >> 3, r = nwg & 7;
        const int xcd = orig & 7, idx = orig >> 3;
        const int tile = (xcd < r ? xcd * (q + 1) : r * (q + 1) + (xcd - r) * q) + idx;
        p0 = tile * 64;
    }

    if (t < 64) {
        int slot = p0 + t;
        bool valid = slot < E;
        int cs = valid ? slot : (E - 1);
        int eg, rr, cc;
        if (edata) {
            int4 ed = edata[cs];
            eg = ed.x; rr = ed.y; cc = ed.z;
        } else {
            eg = perm[cs];
            rr = ei[eg];
            cc = ei[(size_t)E + eg];
        }
        sEid[t] = valid ? eg : -1;
        srow[t] = rr;
        scol[t] = cc;
        float rad = 0.f;
        #pragma unroll
        for (int d3 = 0; d3 < 3; ++d3) {
            float df = coord[(size_t)rr * 3 + d3] - coord[(size_t)cc * 3 + d3];
            float ld = lbox[d3];
            df = (df >  0.5f * ld) ? df - ld : df;
            df = (df < -0.5f * ld) ? df + ld : df;
            rad += df * df;
        }
        sRad[t] = rad;
    } else if (t < 192) {
        sW[t - 64] = We1[(size_t)256 * D + (t - 64)];   // radial row of We1
    }
    __syncthreads();

    // phase 1: gather P[row]+Q[col], + rad*w, SiLU -> sH1 bf16
    {
        const int e = t & 63, q = t >> 6;
        const u16* Pp = Pt + (size_t)srow[e] * D;
        const u16* Qp = Qt + (size_t)scol[e] * D;
        const float rad = sRad[e];
        #pragma unroll
        for (int c0 = 0; c0 < 4; ++c0) {
            int j0 = q * 32 + c0 * 8;
            uint4 pu = *(const uint4*)(Pp + j0);
            uint4 qu = *(const uint4*)(Qp + j0);
            u32 pa[4] = {pu.x, pu.y, pu.z, pu.w};
            u32 qa[4] = {qu.x, qu.y, qu.z, qu.w};
            u32 ow[4];
            #pragma unroll
            for (int k = 0; k < 4; ++k) {
                float w0 = sW[j0 + 2 * k], w1 = sW[j0 + 2 * k + 1];
                float v0 = silu_f(bfl(pa[k]) + bfl(qa[k]) + rad * w0);
                float v1 = silu_f(bfh(pa[k]) + bfh(qa[k]) + rad * w1);
                ow[k] = cvt_pk_bf16(v0, v1);
            }
            *(uint4*)(sH1 + e * SHS + j0) = make_uint4(ow[0], ow[1], ow[2], ow[3]);
        }
    }
    __syncthreads();

    const int lrow = lane & 15;
    const int kg = lane >> 4;
    const int g4 = kg * 4;
    const int nbase = wid * 32;

    // phase 2: GEMM2 (K=128)
    f32x4 acc2[4][2] = {};
    {
        bf16x8 B2[8];
        #pragma unroll
        for (int nn = 0; nn < 2; ++nn)
            #pragma unroll
            for (int s = 0; s < 4; ++s)
                B2[nn * 4 + s] = *(const bf16x8*)(wt + 32768 + (size_t)(nbase + nn * 16 + lrow) * 128 + s * 32 + kg * 8);
        #pragma unroll
        for (int s = 0; s < 4; ++s) {
            bf16x8 a[4];
            #pragma unroll
            for (int m = 0; m < 4; ++m)
                a[m] = *(const bf16x8*)(sH1 + (m * 16 + lrow) * SHS + s * 32 + kg * 8);
            #pragma unroll
            for (int m = 0; m < 4; ++m)
                #pragma unroll
                for (int nn = 0; nn < 2; ++nn)
                    acc2[m][nn] = __builtin_amdgcn_mfma_f32_16x16x32_bf16(a[m], B2[nn * 4 + s], acc2[m][nn], 0, 0, 0);
        }
    }
    __syncthreads();   // sH1 dead before sE16 overwrite

    // phase 3: bias + SiLU -> bf16 buffer (same union)
    #pragma unroll
    for (int nn = 0; nn < 2; ++nn) {
        int outc = nbase + nn * 16 + lrow;
        float bb = be2[outc];
        #pragma unroll
        for (int m = 0; m < 4; ++m)
            #pragma unroll
            for (int r = 0; r < 4; ++r)
                sE16[(m * 16 + g4 + r) * SHS + outc] = cvt1_bf16(silu_f(acc2[m][nn][r] + bb));
    }
    __syncthreads();

    // phase 4: merged ef write (NT) + segmented reduce
    if (agg16) {
        // packed bf16 atomics; thread owns column-pair cp, wave g walks 16 edges
        const int cp = t & 63;
        const int g = t >> 6;
        const int ebeg = g * 16, eend = ebeg + 16;
        float r0 = 0.f, r1 = 0.f;
        int prev = srow[ebeg];
        for (int e = ebeg; e < eend; ++e) {
            int r = srow[e];
            if (r != prev) {
                if (r0 != 0.f || r1 != 0.f)
                    atomic_pk_add_bf16(agg16 + (size_t)prev * D + 2 * cp, cvt_pk_bf16(r0, r1));
                r0 = 0.f; r1 = 0.f; prev = r;
            }
            int eg = sEid[e];
            if (eg >= 0) {
                u32 pk2 = *(const u32*)(sE16 + e * SHS + 2 * cp);
                float v0 = bfl(pk2), v1 = bfh(pk2);
                f32x2 vv = {v0, v1};
                __builtin_nontemporal_store(vv, (f32x2*)&ef_out[(size_t)eg * D + 2 * cp]);
                r0 += v0; r1 += v1;
            }
        }
        if (r0 != 0.f || r1 != 0.f)
            atomic_pk_add_bf16(agg16 + (size_t)prev * D + 2 * cp, cvt_pk_bf16(r0, r1));
    } else {
        const int ct = t & 127;
        const int half = t >> 7;
        const int ebeg = half * 32, eend = ebeg + 32;
        float run = 0.f;
        int prev = srow[ebeg];
        for (int e = ebeg; e < eend; ++e) {
            int r = srow[e];
            if (r != prev) {
                if (run != 0.f) atomicAdd(&aggf[(size_t)prev * D + ct], run);
                run = 0.f; prev = r;
            }
            int eg = sEid[e];
            if (eg >= 0) {
                float v = __uint_as_float((u32)sE16[e * SHS + ct] << 16);
                __builtin_nontemporal_store(v, &ef_out[(size_t)eg * D + ct]);
                run += v;
            }
        }
        if (run != 0.f) atomicAdd(&aggf[(size_t)prev * D + ct], run);
    }
}

// ---------------- edge fallback (f32 staging, own GEMM1) ----------------
__global__ __launch_bounds__(256, 3) void edge_fb_kernel(
    const float* __restrict__ h,
    const int* __restrict__ ei, const int* __restrict__ perm,
    const float* __restrict__ coord, const float* __restrict__ lbox,
    const u16* __restrict__ wt,
    const float* __restrict__ We1, const float* __restrict__ be1,
    const float* __restrict__ be2,
    float* __restrict__ ef_out, float* __restrict__ aggf, int E)
{
    __shared__ __align__(16) u16 sX[64 * SXS];
    __shared__ __align__(16) u16 sH1[64 * SHS];
    __shared__ int srow[64], scol[64], sEid[64];
    __shared__ float sRad[64];

    const int t = threadIdx.x;
    const int lane = t & 63;
    const int wid = t >> 6;

    int p0;
    {
        const int nwg = gridDim.x;
        const int orig = blockIdx.x;
        const int q = nwg >> 3, r = nwg & 7;
        const int xcd = orig & 7, idx = orig >> 3;
        const int tile = (xcd < r ? xcd * (q + 1) : r * (q + 1) + (xcd - r) * q) + idx;
        p0 = tile * 64;
    }

    if (t < 64) {
        int slot = p0 + t;
        int eg = perm[(slot < E) ? slot : (E - 1)];
        sEid[t] = (p0 + t < E) ? eg : -1;
        srow[t] = ei[eg];
        scol[t] = ei[(size_t)E + eg];
    }
    __syncthreads();

    {
        const int e = t & 63;
        const int q = t >> 6;
        const int r = srow[e], c = scol[e];
        const float4* src = (const float4*)((q < 2) ? (h + (size_t)r * D + (q & 1) * 64)
                                                    : (h + (size_t)c * D + (q & 1) * 64));
        u16* dst = sX + e * SXS + q * 64;
        #pragma unroll
        for (int i = 0; i < 8; ++i) {
            float4 a = src[2 * i], b = src[2 * i + 1];
            *(uint4*)(dst + i * 8) = make_uint4(cvt_pk_bf16(a.x, a.y), cvt_pk_bf16(a.z, a.w),
                                               cvt_pk_bf16(b.x, b.y), cvt_pk_bf16(b.z, b.w));
        }
        if (t < 64) {
            int rr = srow[t], cc = scol[t];
            float rad = 0.f;
            #pragma unroll
            for (int d3 = 0; d3 < 3; ++d3) {
                float df = coord[(size_t)rr * 3 + d3] - coord[(size_t)cc * 3 + d3];
                float ld = lbox[d3];
                df = (df >  0.5f * ld) ? df - ld : df;
                df = (df < -0.5f * ld) ? df + ld : df;
                rad += df * df;
            }
            sRad[t] = rad;
        }
    }
    __syncthreads();

    const int lrow = lane & 15;
    const int kg = lane >> 4;
    const int g4 = kg * 4;
    const int nbase = wid * 32;

    f32x4 acc[4][2] = {};
    {
        bf16x8 B1[16];
        #pragma unroll
        for (int nn = 0; nn < 2; ++nn)
            #pragma unroll
            for (int s = 0; s < 8; ++s)
                B1[nn * 8 + s] = *(const bf16x8*)(wt + (size_t)(nbase + nn * 16 + lrow) * 256 + s * 32 + kg * 8);
        #pragma unroll
        for (int s = 0; s < 8; ++s) {
            bf16x8 a[4];
            #pragma unroll
            for (int m = 0; m < 4; ++m)
                a[m] = *(const bf16x8*)(sX + (m * 16 + lrow) * SXS + s * 32 + kg * 8);
            #pragma unroll
            for (int m = 0; m < 4; ++m)
                #pragma unroll
                for (int nn = 0; nn < 2; ++nn)
                    acc[m][nn] = __builtin_amdgcn_mfma_f32_16x16x32_bf16(a[m], B1[nn * 8 + s], acc[m][nn], 0, 0, 0);
        }
    }

    #pragma unroll
    for (int nn = 0; nn < 2; ++nn) {
        int outc = nbase + nn * 16 + lrow;
        float wl = We1[(size_t)256 * D + outc];
        float bb = be1[outc];
        #pragma unroll
        for (int m = 0; m < 4; ++m)
            #pragma unroll
            for (int r = 0; r < 4; ++r) {
                int e = m * 16 + g4 + r;
                float v = acc[m][nn][r] + sRad[e] * wl + bb;
                sH1[e * SHS + outc] = cvt1_bf16(silu_f(v));
            }
    }
    __syncthreads();

    f32x4 acc2[4][2] = {};
    {
        bf16x8 B2[8];
        #pragma unroll
        for (int nn = 0; nn < 2; ++nn)
            #pragma unroll
            for (int s = 0; s < 4; ++s)
                B2[nn * 4 + s] = *(const bf16x8*)(wt + 32768 + (size_t)(nbase + nn * 16 + lrow) * 128 + s * 32 + kg * 8);
        #pragma unroll
        for (int s = 0; s < 4; ++s) {
            bf16x8 a[4];
            #pragma unroll
            for (int m = 0; m < 4; ++m)
                a[m] = *(const bf16x8*)(sH1 + (m * 16 + lrow) * SHS + s * 32 + kg * 8);
            #pragma unroll
            for (int m = 0; m < 4; ++m)
                #pragma unroll
                for (int nn = 0; nn < 2; ++nn)
                    acc2[m][nn] = __builtin_amdgcn_mfma_f32_16x16x32_bf16(a[m], B2[nn * 4 + s], acc2[m][nn], 0, 0, 0);
        }
    }
    __syncthreads();

    float* sXf = (float*)sX;
    #pragma unroll
    for (int nn = 0; nn < 2; ++nn) {
        int outc = nbase + nn * 16 + lrow;
        float bb = be2[outc];
        #pragma unroll
        for (int m = 0; m < 4; ++m)
            #pragma unroll
            for (int r = 0; r < 4; ++r)
                sXf[(m * 16 + g4 + r) * SFS + outc] = silu_f(acc2[m][nn][r] + bb);
    }
    __syncthreads();

    {
        const int ct = t & 127;
        const int half = t >> 7;
        const int ebeg = half * 32, eend = ebeg + 32;
        float run = 0.f;
        int prev = srow[ebeg];
        for (int e = ebeg; e < eend; ++e) {
            int r = srow[e];
            if (r != prev) {
                if (run != 0.f) atomicAdd(&aggf[(size_t)prev * D + ct], run);
                run = 0.f; prev = r;
            }
            int eg = sEid[e];
            if (eg >= 0) {
                float v = sXf[e * SFS + ct];
                __builtin_nontemporal_store(v, &ef_out[(size_t)eg * D + ct]);
                run += v;
            }
        }
        if (run != 0.f) atomicAdd(&aggf[(size_t)prev * D + ct], run);
    }
}

// ---------------- node model (aliased LDS, 4 blocks/CU) ----------------
__global__ __launch_bounds__(256, 4) void node_kernel(
    const float* __restrict__ h, const float* __restrict__ aggf,
    const u16* __restrict__ agg16,
    const u16* __restrict__ wt,
    const float* __restrict__ bn1, const float* __restrict__ bn2,
    float* __restrict__ h_out, int N)
{
    __shared__ __align__(16) u16 uni[64 * SXS];   // 33792 B union: sX / sH1 / sXf
    u16* sX = uni;
    u16* sH1 = uni;
    float* sXf = (float*)uni;

    const int t = threadIdx.x;
    const int lane = t & 63;
    const int wid = t >> 6;
    const int n0 = blockIdx.x * 64;

    {
        const int e = t & 63;
        const int q = t >> 6;
        int ng = n0 + e; int ns = (ng < N) ? ng : N - 1;
        u16* dst = sX + e * SXS + q * 64;
        if (q >= 2 && agg16) {
            const u16* src = agg16 + (size_t)ns * D + (q & 1) * 64;
            #pragma unroll
            for (int i = 0; i < 8; ++i)
                *(uint4*)(dst + i * 8) = *(const uint4*)(src + i * 8);
        } else {
            const float4* src = (const float4*)(((q < 2) ? h : aggf) + (size_t)ns * D + (q & 1) * 64);
            #pragma unroll
            for (int i = 0; i < 8; ++i) {
                float4 a = src[2 * i], b = src[2 * i + 1];
                *(uint4*)(dst + i * 8) = make_uint4(cvt_pk_bf16(a.x, a.y), cvt_pk_bf16(a.z, a.w),
                                                   cvt_pk_bf16(b.x, b.y), cvt_pk_bf16(b.z, b.w));
            }
        }
    }
    __syncthreads();

    const int lrow = lane & 15;
    const int kg = lane >> 4;
    const int g4 = kg * 4;
    const int nbase = wid * 32;

    f32x4 acc[4][2] = {};
    {
        bf16x8 B1[16];
        #pragma unroll
        for (int nn = 0; nn < 2; ++nn)
            #pragma unroll
            for (int s = 0; s < 8; ++s)
                B1[nn * 8 + s] = *(const bf16x8*)(wt + 49152 + (size_t)(nbase + nn * 16 + lrow) * 256 + s * 32 + kg * 8);
        #pragma unroll
        for (int s = 0; s < 8; ++s) {
            bf16x8 a[4];
            #pragma unroll
            for (int m = 0; m < 4; ++m)
                a[m] = *(const bf16x8*)(sX + (m * 16 + lrow) * SXS + s * 32 + kg * 8);
            #pragma unroll
            for (int m = 0; m < 4; ++m)
                #pragma unroll
                for (int nn = 0; nn < 2; ++nn)
                    acc[m][nn] = __builtin_amdgcn_mfma_f32_16x16x32_bf16(a[m], B1[nn * 8 + s], acc[m][nn], 0, 0, 0);
        }
    }
    __syncthreads();   // sX dead before sH1 overwrite

    #pragma unroll
    for (int nn = 0; nn < 2; ++nn) {
        int outc = nbase + nn * 16 + lrow;
        float bb = bn1[outc];
        #pragma unroll
        for (int m = 0; m < 4; ++m)
            #pragma unroll
            for (int r = 0; r < 4; ++r)
                sH1[(m * 16 + g4 + r) * SHS + outc] = cvt1_bf16(silu_f(acc[m][nn][r] + bb));
    }
    __syncthreads();

    f32x4 acc2[4][2] = {};
    {
        bf16x8 B2[8];
        #pragma unroll
        for (int nn = 0; nn < 2; ++nn)
            #pragma unroll
            for (int s = 0; s < 4; ++s)
                B2[nn * 4 + s] = *(const bf16x8*)(wt + 81920 + (size_t)(nbase + nn * 16 + lrow) * 128 + s * 32 + kg * 8);
        #pragma unroll
        for (int s = 0; s < 4; ++s) {
            bf16x8 a[4];
            #pragma unroll
            for (int m = 0; m < 4; ++m)
                a[m] = *(const bf16x8*)(sH1 + (m * 16 + lrow) * SHS + s * 32 + kg * 8);
            #pragma unroll
            for (int m = 0; m < 4; ++m)
                #pragma unroll
                for (int nn = 0; nn < 2; ++nn)
                    acc2[m][nn] = __builtin_amdgcn_mfma_f32_16x16x32_bf16(a[m], B2[nn * 4 + s], acc2[m][nn], 0, 0, 0);
        }
    }
    __syncthreads();   // sH1 dead before sXf overwrite

    #pragma unroll
    for (int nn = 0; nn < 2; ++nn) {
        int outc = nbase + nn * 16 + lrow;
        float bb = bn2[outc];
        #pragma unroll
        for (int m = 0; m < 4; ++m)
            #pragma unroll
            for (int r = 0; r < 4; ++r)
                sXf[(m * 16 + g4 + r) * SFS + outc] = acc2[m][nn][r] + bb;
    }
    __syncthreads();

    {
        const int f4 = t & 31;
        const int nb = t >> 5;
        #pragma unroll
        for (int i = 0; i < 8; ++i) {
            int nl = nb + i * 8;
            int ng = n0 + nl;
            if (ng < N) {
                f32x4 v = *(const f32x4*)&sXf[nl * SFS + f4 * 4];
                const f32x4 hv = *(const f32x4*)&h[(size_t)ng * D + f4 * 4];
                v += hv;
                __builtin_nontemporal_store(v, (f32x4*)&h_out[(size_t)ng * D + f4 * 4]);
            }
        }
    }
}

extern "C" void kernel_launch(void* const* d_in, const int* in_sizes, int n_in,
                              void* d_out, int out_size, void* d_ws, size_t ws_size,
                              hipStream_t stream) {
    const float* h     = (const float*)d_in[0];
    const int*   ei    = (const int*)d_in[1];
    const float* coord = (const float*)d_in[2];
    const float* lbox  = (const float*)d_in[4];
    const float* We1   = (const float*)d_in[5];
    const float* be1   = (const float*)d_in[6];
    const float* We2   = (const float*)d_in[7];
    const float* be2   = (const float*)d_in[8];
    const float* Wn1   = (const float*)d_in[9];
    const float* bn1   = (const float*)d_in[10];
    const float* Wn2   = (const float*)d_in[11];
    const float* bn2   = (const float*)d_in[12];

    const int N = in_sizes[0] / D;
    const int E = in_sizes[1] / 2;

    float* out       = (float*)d_out;
    float* h_out     = out;                       // [N,128]
    float* coord_out = out + (size_t)N * D;       // [N,3]
    float* ef_out    = coord_out + (size_t)N * 3; // [E,128]
    float* aggf      = h_out;                     // f32 agg fallback (in-place)

    // workspace layout: wt | offs | cursor | bsum | perm | Pt | Qt | edata | agg16
    int* wsi = (int*)d_ws;
    u16* wt     = (u16*)d_ws;                     // 98304 u16 = 49152 ints
    int* offs   = wsi + 49152;                    // N+1 (padded N+8)
    int* cursor = offs + (N + 8);                 // N   (padded N+8)
    int* bsum   = cursor + (N + 8);               // 64
    int* perm   = bsum + 64;                      // E
    u16* Pt     = (u16*)(perm + E);               // N*128 bf16
    u16* Qt     = Pt + (size_t)N * D;             // N*128 bf16
    int4* edata = (int4*)(((uintptr_t)(Qt + (size_t)N * D) + 15) & ~(uintptr_t)15); // E int4
    u16* agg16  = (u16*)(edata + E);              // N*128 bf16

    size_t need_pq  = (size_t)((char*)(Qt + (size_t)N * D) - (char*)d_ws);
    size_t need_ed  = (size_t)((char*)(edata + E) - (char*)d_ws);
    size_t need_a16 = (size_t)((char*)(agg16 + (size_t)N * D) - (char*)d_ws);
    const bool use_pq  = ws_size >= need_pq;
    const bool use_ed  = use_pq && ws_size >= need_ed;
    const bool use_a16 = use_ed && ws_size >= need_a16;
    int4* edp  = use_ed ? edata : nullptr;
    u16*  a16p = use_a16 ? agg16 : nullptr;

    const int nb1 = (N + 1 + 1023) / 1024;        // scan1 blocks (<=64)

    prep_weights<<<384, 256, 0, stream>>>(We1, We2, Wn1, Wn2, wt);
    if (use_pq) {
        const int NBn = (N + 63) / 64;
        const int NBc = (N * 3 + 255) / 256;
        pq_kernel<<<NBn + NBc, 256, 0, stream>>>(h, wt, be1, Pt, Qt, cursor, N,
                                                 coord, lbox, coord_out, N * 3, NBn);
    } else {
        hipMemsetAsync(cursor, 0, (size_t)N * sizeof(int), stream);
        coord_kernel<<<(N * 3 + 255) / 256, 256, 0, stream>>>(coord, lbox, coord_out, N * 3);
    }

    // zero agg accumulator
    if (use_a16)
        hipMemsetAsync(agg16, 0, (size_t)N * D * sizeof(u16), stream);
    else
        hipMemsetAsync(aggf, 0, (size_t)N * D * sizeof(float), stream);

    // CSR build
    hist_kernel<<<(E + 255) / 256, 256, 0, stream>>>(ei, cursor, E);
    scan1_kernel<<<nb1, 256, 0, stream>>>(cursor, offs, bsum, N + 1);
    scan2_kernel<<<1, 64, 0, stream>>>(bsum, nb1);
    scan3_kernel<<<(N + 1 + 255) / 256, 256, 0, stream>>>(offs, bsum, cursor, N + 1);
    scatter_kernel<<<(E + 255) / 256, 256, 0, stream>>>(ei, cursor, perm, edp, E);

    if (use_pq)
        edge_pq_kernel<<<(E + 63) / 64, 256, 0, stream>>>(
            Pt, Qt, ei, perm, edp, coord, lbox, wt, We1, be2, ef_out, aggf, a16p, E);
    else
        edge_fb_kernel<<<(E + 63) / 64, 256, 0, stream>>>(
            h, ei, perm, coord, lbox, wt, We1, be1, be2, ef_out, aggf, E);

    node_kernel<<<(N + 63) / 64, 256, 0, stream>>>(
        h, aggf, a16p, wt, bn1, bn2, h_out, N);
}

// Round 13
// 243.925 us; speedup vs baseline: 1.2165x; 1.0238x over previous
//
#include <hip/hip_runtime.h>
#include <math.h>

#define D 128
#define SXS 264   // node/fallback sX stride (u16)
#define SHS 132   // activation stride (u16): 66 dwords == 2 mod 8 -> conflict-free epi
#define SFS 132   // f32 out-buffer stride (dwords), fallback path

typedef unsigned int u32;
typedef unsigned short u16;
typedef __attribute__((ext_vector_type(8))) short bf16x8;
typedef __attribute__((ext_vector_type(4))) float f32x4;
typedef __attribute__((ext_vector_type(2))) float f32x2;

__device__ __forceinline__ float bfl(u32 u) { return __uint_as_float(u << 16); }
__device__ __forceinline__ float bfh(u32 u) { return __uint_as_float(u & 0xFFFF0000u); }
__device__ __forceinline__ u16 f2bf(float f) {
    u32 u = __float_as_uint(f);
    return (u16)((u + 0x7FFFu + ((u >> 16) & 1u)) >> 16); // RNE (cold paths)
}
// HW packed f32->bf16 (RNE), 1 VALU op
__device__ __forceinline__ u32 cvt_pk_bf16(float lo, float hi) {
    u32 r;
    asm("v_cvt_pk_bf16_f32 %0, %1, %2" : "=v"(r) : "v"(lo), "v"(hi));
    return r;
}
__device__ __forceinline__ u16 cvt1_bf16(float v) { return (u16)cvt_pk_bf16(v, v); }
// fast SiLU: v_exp + v_rcp (1-ulp approx rcp — invisible at bf16 output precision)
// vs IEEE divide (~10-12 VALU ops without -ffast-math)
__device__ __forceinline__ float silu_f(float x) {
    float e = __expf(-x);
    return x * __builtin_amdgcn_rcpf(1.0f + e);
}
// device-scope packed bf16 atomic add (gfx940+), no return
__device__ __forceinline__ void atomic_pk_add_bf16(u16* addr, u32 pk) {
    asm volatile("global_atomic_pk_add_bf16 %0, %1, off sc1"
                 :: "v"(addr), "v"(pk) : "memory");
}

// ---------------- coord: out = remainder(coord, l) (standalone, fallback path) ----------------
__global__ void coord_kernel(const float* __restrict__ coord,
                             const float* __restrict__ lbox,
                             float* __restrict__ out, int n3) {
    int i = blockIdx.x * 256 + threadIdx.x;
    if (i < n3) {
        float ld = lbox[i % 3];
        float c = coord[i];
        float r = fmodf(c, ld);
        if (r < 0.f) r += ld;
        out[i] = r;
    }
}

// ---------------- weight prep: bf16 transposed Wt[n][k] into ws ----------------
__global__ void prep_weights(const float* __restrict__ We1, const float* __restrict__ We2,
                             const float* __restrict__ Wn1, const float* __restrict__ Wn2,
                             u16* __restrict__ wt) {
    int i = blockIdx.x * 256 + threadIdx.x;
    if (i < 32768)        { int n = i >> 8, k = i & 255;              wt[i] = f2bf(We1[(size_t)k*D + n]); }
    else if (i < 49152)   { int j = i - 32768; int n = j >> 7, k = j & 127; wt[i] = f2bf(We2[(size_t)k*D + n]); }
    else if (i < 81920)   { int j = i - 49152; int n = j >> 8, k = j & 255; wt[i] = f2bf(Wn1[(size_t)k*D + n]); }
    else if (i < 98304)   { int j = i - 81920; int n = j >> 7, k = j & 127; wt[i] = f2bf(Wn2[(size_t)k*D + n]); }
}

// ---------------- CSR build ----------------
__global__ void hist_kernel(const int* __restrict__ ei, int* __restrict__ cnt, int E) {
    int e = blockIdx.x * 256 + threadIdx.x;
    if (e < E) atomicAdd(&cnt[ei[e]], 1);
}

__global__ void scan1_kernel(const int* __restrict__ cnt, int* __restrict__ offs,
                             int* __restrict__ bsum, int n /* = N+1 */) {
    __shared__ int s[256];
    int t = threadIdx.x, b = blockIdx.x;
    int base = b * 1024 + t * 4;
    int v[4];
    #pragma unroll
    for (int i = 0; i < 4; ++i) { int idx = base + i; v[i] = (idx < n - 1) ? cnt[idx] : 0; }
    int lsum = v[0] + v[1] + v[2] + v[3];
    s[t] = lsum; __syncthreads();
    #pragma unroll
    for (int off = 1; off < 256; off <<= 1) {
        int x = (t >= off) ? s[t - off] : 0; __syncthreads();
        s[t] += x; __syncthreads();
    }
    int run = s[t] - lsum;
    #pragma unroll
    for (int i = 0; i < 4; ++i) { int idx = base + i; if (idx < n) offs[idx] = run; run += v[i]; }
    if (t == 255) bsum[b] = s[255];
}

__global__ void scan2_kernel(int* __restrict__ bsum, int nb) {
    __shared__ int s[64];
    int t = threadIdx.x;
    int orig = (t < nb) ? bsum[t] : 0;
    s[t] = orig; __syncthreads();
    #pragma unroll
    for (int off = 1; off < 64; off <<= 1) {
        int x = (t >= off) ? s[t - off] : 0; __syncthreads();
        s[t] += x; __syncthreads();
    }
    if (t < nb) bsum[t] = s[t] - orig;
}

__global__ void scan3_kernel(int* __restrict__ offs, const int* __restrict__ bsum,
                             int* __restrict__ cursor, int n) {
    int i = blockIdx.x * 256 + threadIdx.x;
    if (i < n) {
        int v = offs[i] + bsum[i >> 10];
        offs[i] = v;
        if (i < n - 1) cursor[i] = v;
    }
}

// writes either perm[p]=e (fallback) or edata[p]={e,row,col,0}
__global__ void scatter_kernel(const int* __restrict__ ei, int* __restrict__ cursor,
                               int* __restrict__ perm, int4* __restrict__ edata, int E) {
    int e = blockIdx.x * 256 + threadIdx.x;
    if (e < E) {
        int r = ei[e];
        int c = ei[(size_t)E + e];
        int p = atomicAdd(&cursor[r], 1);
        if (edata) edata[p] = make_int4(e, r, c, 0);
        else perm[p] = e;
    }
}

// ---------------- P/Q precompute (+ coord tail blocks): P = h@W_top + be1, Q = h@W_mid ----------------
__global__ __launch_bounds__(256, 4) void pq_kernel(
    const float* __restrict__ h, const u16* __restrict__ wt,
    const float* __restrict__ be1,
    u16* __restrict__ Pt, u16* __restrict__ Qt,
    int* __restrict__ cursor, int N,
    const float* __restrict__ coord, const float* __restrict__ lbox,
    float* __restrict__ coord_out, int n3, int NBn)
{
    __shared__ __align__(16) u16 sA[64 * SHS];
    __shared__ __align__(16) u16 sO[64 * SHS];

    const int t = threadIdx.x;

    // tail blocks: coord remainder
    if (blockIdx.x >= NBn) {
        int i = (blockIdx.x - NBn) * 256 + t;
        if (i < n3) {
            float ld = lbox[i % 3];
            float c = coord[i];
            float r = fmodf(c, ld);
            if (r < 0.f) r += ld;
            coord_out[i] = r;
        }
        return;
    }

    const int lane = t & 63;
    const int wid = t >> 6;
    const int n0 = blockIdx.x * 64;

    // zero the CSR count array (replaces a fill dispatch)
    if (t < 64) { int zi = n0 + t; if (zi < N) cursor[zi] = 0; }

    // stage h (f32 -> bf16) [64][128]
    {
        const int e = t & 63, q = t >> 6;
        int ng = n0 + e; int ns = (ng < N) ? ng : N - 1;
        const float4* src = (const float4*)(h + (size_t)ns * D + q * 32);
        u16* dst = sA + e * SHS + q * 32;
        #pragma unroll
        for (int c = 0; c < 4; ++c) {
            float4 a = src[2 * c], b = src[2 * c + 1];
            *(uint4*)(dst + c * 8) = make_uint4(cvt_pk_bf16(a.x, a.y), cvt_pk_bf16(a.z, a.w),
                                               cvt_pk_bf16(b.x, b.y), cvt_pk_bf16(b.z, b.w));
        }
    }
    __syncthreads();

    const int lrow = lane & 15;
    const int kg = lane >> 4;
    const int g4 = kg * 4;
    const int nbase = wid * 32;

    f32x4 accP[4][2] = {}, accQ[4][2] = {};
    {
        bf16x8 Bt[8], Bm[8];
        #pragma unroll
        for (int nn = 0; nn < 2; ++nn)
            #pragma unroll
            for (int s = 0; s < 4; ++s) {
                const u16* bp = wt + (size_t)(nbase + nn * 16 + lrow) * 256 + s * 32 + kg * 8;
                Bt[nn * 4 + s] = *(const bf16x8*)bp;
                Bm[nn * 4 + s] = *(const bf16x8*)(bp + 128);
            }
        #pragma unroll
        for (int s = 0; s < 4; ++s) {
            bf16x8 a[4];
            #pragma unroll
            for (int m = 0; m < 4; ++m)
                a[m] = *(const bf16x8*)(sA + (m * 16 + lrow) * SHS + s * 32 + kg * 8);
            #pragma unroll
            for (int m = 0; m < 4; ++m)
                #pragma unroll
                for (int nn = 0; nn < 2; ++nn) {
                    accP[m][nn] = __builtin_amdgcn_mfma_f32_16x16x32_bf16(a[m], Bt[nn * 4 + s], accP[m][nn], 0, 0, 0);
                    accQ[m][nn] = __builtin_amdgcn_mfma_f32_16x16x32_bf16(a[m], Bm[nn * 4 + s], accQ[m][nn], 0, 0, 0);
                }
        }
    }

    // --- P: +be1, pack bf16, coalesced copy-out ---
    #pragma unroll
    for (int nn = 0; nn < 2; ++nn) {
        int outc = nbase + nn * 16 + lrow;
        float bb = be1[outc];
        #pragma unroll
        for (int m = 0; m < 4; ++m)
            #pragma unroll
            for (int r = 0; r < 4; ++r)
                sO[(m * 16 + g4 + r) * SHS + outc] = cvt1_bf16(accP[m][nn][r] + bb);
    }
    __syncthreads();
    {
        const int f4 = t & 15, rb = t >> 4;
        #pragma unroll
        for (int p = 0; p < 4; ++p) {
            int row = rb + p * 16;
            int ng = n0 + row;
            if (ng < N)
                *(uint4*)(Pt + (size_t)ng * D + f4 * 8) = *(const uint4*)(sO + row * SHS + f4 * 8);
        }
    }
    __syncthreads();
    // --- Q ---
    #pragma unroll
    for (int nn = 0; nn < 2; ++nn) {
        int outc = nbase + nn * 16 + lrow;
        #pragma unroll
        for (int m = 0; m < 4; ++m)
            #pragma unroll
            for (int r = 0; r < 4; ++r)
                sO[(m * 16 + g4 + r) * SHS + outc] = cvt1_bf16(accQ[m][nn][r]);
    }
    __syncthreads();
    {
        const int f4 = t & 15, rb = t >> 4;
        #pragma unroll
        for (int p = 0; p < 4; ++p) {
            int row = rb + p * 16;
            int ng = n0 + row;
            if (ng < N)
                *(uint4*)(Qt + (size_t)ng * D + f4 * 8) = *(const uint4*)(sO + row * SHS + f4 * 8);
        }
    }
}

// ---------------- edge model (P/Q path; bf16 LDS union; 8 blocks/CU) ----------------
__global__ __launch_bounds__(256, 8) void edge_pq_kernel(
    const u16* __restrict__ Pt, const u16* __restrict__ Qt,
    const int* __restrict__ ei, const int* __restrict__ perm,
    const int4* __restrict__ edata,
    const float* __restrict__ coord, const float* __restrict__ lbox,
    const u16* __restrict__ wt, const float* __restrict__ We1,
    const float* __restrict__ be2,
    float* __restrict__ ef_out, float* __restrict__ aggf,
    u16* __restrict__ agg16, int E)
{
    __shared__ __align__(16) u16 uni[64 * SHS];   // 16896 B union: sH1 / sE16
    __shared__ int srow[64], scol[64], sEid[64];
    __shared__ float sRad[64];
    __shared__ float sW[128];
    u16* sH1 = uni;
    u16* sE16 = uni;

    const int t = threadIdx.x;
    const int lane = t & 63;
    const int wid = t >> 6;

    // bijective XCD swizzle (m204)
    int p0;
    {
        const int nwg = gridDim.x;
        const int orig = blockIdx.x;
        const int q = nwg >> 3, r = nwg & 7;
        const int xcd = orig & 7, idx = orig >> 3;
        const int tile = (xcd < r ? xcd * (q + 1) : r * (q + 1) + (xcd - r) * q) + idx;
        p0 = tile * 64;
    }

    if (t < 64) {
        int slot = p0 + t;
        bool valid = slot < E;
        int cs = valid ? slot : (E - 1);
        int eg, rr, cc;
        if (edata) {
            int4 ed = edata[cs];
            eg = ed.x; rr = ed.y; cc = ed.z;
        } else {
            eg = perm[cs];
            rr = ei[eg];
            cc = ei[(size_t)E + eg];
        }
        sEid[t] = valid ? eg : -1;
        srow[t] = rr;
        scol[t] = cc;
        float rad = 0.f;
        #pragma unroll
        for (int d3 = 0; d3 < 3; ++d3) {
            float df = coord[(size_t)rr * 3 + d3] - coord[(size_t)cc * 3 + d3];
            float ld = lbox[d3];
            df = (df >  0.5f * ld) ? df - ld : df;
            df = (df < -0.5f * ld) ? df + ld : df;
            rad += df * df;
        }
        sRad[t] = rad;
    } else if (t < 192) {
        sW[t - 64] = We1[(size_t)256 * D + (t - 64)];   // radial row of We1
    }
    __syncthreads();

    // phase 1: gather P[row]+Q[col], + rad*w, SiLU -> sH1 bf16
    {
        const int e = t & 63, q = t >> 6;
        const u16* Pp = Pt + (size_t)srow[e] * D;
        const u16* Qp = Qt + (size_t)scol[e] * D;
        const float rad = sRad[e];
        #pragma unroll
        for (int c0 = 0; c0 < 4; ++c0) {
            int j0 = q * 32 + c0 * 8;
            uint4 pu = *(const uint4*)(Pp + j0);
            uint4 qu = *(const uint4*)(Qp + j0);
            u32 pa[4] = {pu.x, pu.y, pu.z, pu.w};
            u32 qa[4] = {qu.x, qu.y, qu.z, qu.w};
            u32 ow[4];
            #pragma unroll
            for (int k = 0; k < 4; ++k) {
                float w0 = sW[j0 + 2 * k], w1 = sW[j0 + 2 * k + 1];
                float v0 = silu_f(bfl(pa[k]) + bfl(qa[k]) + rad * w0);
                float v1 = silu_f(bfh(pa[k]) + bfh(qa[k]) + rad * w1);
                ow[k] = cvt_pk_bf16(v0, v1);
            }
            *(uint4*)(sH1 + e * SHS + j0) = make_uint4(ow[0], ow[1], ow[2], ow[3]);
        }
    }
    __syncthreads();

    const int lrow = lane & 15;
    const int kg = lane >> 4;
    const int g4 = kg * 4;
    const int nbase = wid * 32;

    // phase 2: GEMM2 (K=128)
    f32x4 acc2[4][2] = {};
    {
        bf16x8 B2[8];
        #pragma unroll
        for (int nn = 0; nn < 2; ++nn)
            #pragma unroll
            for (int s = 0; s < 4; ++s)
                B2[nn * 4 + s] = *(const bf16x8*)(wt + 32768 + (size_t)(nbase + nn * 16 + lrow) * 128 + s * 32 + kg * 8);
        #pragma unroll
        for (int s = 0; s < 4; ++s) {
            bf16x8 a[4];
            #pragma unroll
            for (int m = 0; m < 4; ++m)
                a[m] = *(const bf16x8*)(sH1 + (m * 16 + lrow) * SHS + s * 32 + kg * 8);
            #pragma unroll
            for (int m = 0; m < 4; ++m)
                #pragma unroll
                for (int nn = 0; nn < 2; ++nn)
                    acc2[m][nn] = __builtin_amdgcn_mfma_f32_16x16x32_bf16(a[m], B2[nn * 4 + s], acc2[m][nn], 0, 0, 0);
        }
    }
    __syncthreads();   // sH1 dead before sE16 overwrite

    // phase 3: bias + SiLU -> bf16 buffer (same union)
    #pragma unroll
    for (int nn = 0; nn < 2; ++nn) {
        int outc = nbase + nn * 16 + lrow;
        float bb = be2[outc];
        #pragma unroll
        for (int m = 0; m < 4; ++m)
            #pragma unroll
            for (int r = 0; r < 4; ++r)
                sE16[(m * 16 + g4 + r) * SHS + outc] = cvt1_bf16(silu_f(acc2[m][nn][r] + bb));
    }
    __syncthreads();

    // phase 4: merged ef write (NT) + segmented reduce
    if (agg16) {
        // packed bf16 atomics; thread owns column-pair cp, wave g walks 16 edges
        const int cp = t & 63;
        const int g = t >> 6;
        const int ebeg = g * 16, eend = ebeg + 16;
        float r0 = 0.f, r1 = 0.f;
        int prev = srow[ebeg];
        for (int e = ebeg; e < eend; ++e) {
            int r = srow[e];
            if (r != prev) {
                if (r0 != 0.f || r1 != 0.f)
                    atomic_pk_add_bf16(agg16 + (size_t)prev * D + 2 * cp, cvt_pk_bf16(r0, r1));
                r0 = 0.f; r1 = 0.f; prev = r;
            }
            int eg = sEid[e];
            if (eg >= 0) {
                u32 pk2 = *(const u32*)(sE16 + e * SHS + 2 * cp);
                float v0 = bfl(pk2), v1 = bfh(pk2);
                f32x2 vv = {v0, v1};
                __builtin_nontemporal_store(vv, (f32x2*)&ef_out[(size_t)eg * D + 2 * cp]);
                r0 += v0; r1 += v1;
            }
        }
        if (r0 != 0.f || r1 != 0.f)
            atomic_pk_add_bf16(agg16 + (size_t)prev * D + 2 * cp, cvt_pk_bf16(r0, r1));
    } else {
        const int ct = t & 127;
        const int half = t >> 7;
        const int ebeg = half * 32, eend = ebeg + 32;
        float run = 0.f;
        int prev = srow[ebeg];
        for (int e = ebeg; e < eend; ++e) {
            int r = srow[e];
            if (r != prev) {
                if (run != 0.f) atomicAdd(&aggf[(size_t)prev * D + ct], run);
                run = 0.f; prev = r;
            }
            int eg = sEid[e];
            if (eg >= 0) {
                float v = __uint_as_float((u32)sE16[e * SHS + ct] << 16);
                __builtin_nontemporal_store(v, &ef_out[(size_t)eg * D + ct]);
                run += v;
            }
        }
        if (run != 0.f) atomicAdd(&aggf[(size_t)prev * D + ct], run);
    }
}

// ---------------- edge fallback (f32 staging, own GEMM1) ----------------
__global__ __launch_bounds__(256, 3) void edge_fb_kernel(
    const float* __restrict__ h,
    const int* __restrict__ ei, const int* __restrict__ perm,
    const float* __restrict__ coord, const float* __restrict__ lbox,
    const u16* __restrict__ wt,
    const float* __restrict__ We1, const float* __restrict__ be1,
    const float* __restrict__ be2,
    float* __restrict__ ef_out, float* __restrict__ aggf, int E)
{
    __shared__ __align__(16) u16 sX[64 * SXS];
    __shared__ __align__(16) u16 sH1[64 * SHS];
    __shared__ int srow[64], scol[64], sEid[64];
    __shared__ float sRad[64];

    const int t = threadIdx.x;
    const int lane = t & 63;
    const int wid = t >> 6;

    int p0;
    {
        const int nwg = gridDim.x;
        const int orig = blockIdx.x;
        const int q = nwg >> 3, r = nwg & 7;
        const int xcd = orig & 7, idx = orig >> 3;
        const int tile = (xcd < r ? xcd * (q + 1) : r * (q + 1) + (xcd - r) * q) + idx;
        p0 = tile * 64;
    }

    if (t < 64) {
        int slot = p0 + t;
        int eg = perm[(slot < E) ? slot : (E - 1)];
        sEid[t] = (p0 + t < E) ? eg : -1;
        srow[t] = ei[eg];
        scol[t] = ei[(size_t)E + eg];
    }
    __syncthreads();

    {
        const int e = t & 63;
        const int q = t >> 6;
        const int r = srow[e], c = scol[e];
        const float4* src = (const float4*)((q < 2) ? (h + (size_t)r * D + (q & 1) * 64)
                                                    : (h + (size_t)c * D + (q & 1) * 64));
        u16* dst = sX + e * SXS + q * 64;
        #pragma unroll
        for (int i = 0; i < 8; ++i) {
            float4 a = src[2 * i], b = src[2 * i + 1];
            *(uint4*)(dst + i * 8) = make_uint4(cvt_pk_bf16(a.x, a.y), cvt_pk_bf16(a.z, a.w),
                                               cvt_pk_bf16(b.x, b.y), cvt_pk_bf16(b.z, b.w));
        }
        if (t < 64) {
            int rr = srow[t], cc = scol[t];
            float rad = 0.f;
            #pragma unroll
            for (int d3 = 0; d3 < 3; ++d3) {
                float df = coord[(size_t)rr * 3 + d3] - coord[(size_t)cc * 3 + d3];
                float ld = lbox[d3];
                df = (df >  0.5f * ld) ? df - ld : df;
                df = (df < -0.5f * ld) ? df + ld : df;
                rad += df * df;
            }
            sRad[t] = rad;
        }
    }
    __syncthreads();

    const int lrow = lane & 15;
    const int kg = lane >> 4;
    const int g4 = kg * 4;
    const int nbase = wid * 32;

    f32x4 acc[4][2] = {};
    {
        bf16x8 B1[16];
        #pragma unroll
        for (int nn = 0; nn < 2; ++nn)
            #pragma unroll
            for (int s = 0; s < 8; ++s)
                B1[nn * 8 + s] = *(const bf16x8*)(wt + (size_t)(nbase + nn * 16 + lrow) * 256 + s * 32 + kg * 8);
        #pragma unroll
        for (int s = 0; s < 8; ++s) {
            bf16x8 a[4];
            #pragma unroll
            for (int m = 0; m < 4; ++m)
                a[m] = *(const bf16x8*)(sX + (m * 16 + lrow) * SXS + s * 32 + kg * 8);
            #pragma unroll
            for (int m = 0; m < 4; ++m)
                #pragma unroll
                for (int nn = 0; nn < 2; ++nn)
                    acc[m][nn] = __builtin_amdgcn_mfma_f32_16x16x32_bf16(a[m], B1[nn * 8 + s], acc[m][nn], 0, 0, 0);
        }
    }

    #pragma unroll
    for (int nn = 0; nn < 2; ++nn) {
        int outc = nbase + nn * 16 + lrow;
        float wl = We1[(size_t)256 * D + outc];
        float bb = be1[outc];
        #pragma unroll
        for (int m = 0; m < 4; ++m)
            #pragma unroll
            for (int r = 0; r < 4; ++r) {
                int e = m * 16 + g4 + r;
                float v = acc[m][nn][r] + sRad[e] * wl + bb;
                sH1[e * SHS + outc] = cvt1_bf16(silu_f(v));
            }
    }
    __syncthreads();

    f32x4 acc2[4][2] = {};
    {
        bf16x8 B2[8];
        #pragma unroll
        for (int nn = 0; nn < 2; ++nn)
            #pragma unroll
            for (int s = 0; s < 4; ++s)
                B2[nn * 4 + s] = *(const bf16x8*)(wt + 32768 + (size_t)(nbase + nn * 16 + lrow) * 128 + s * 32 + kg * 8);
        #pragma unroll
        for (int s = 0; s < 4; ++s) {
            bf16x8 a[4];
            #pragma unroll
            for (int m = 0; m < 4; ++m)
                a[m] = *(const bf16x8*)(sH1 + (m * 16 + lrow) * SHS + s * 32 + kg * 8);
            #pragma unroll
            for (int m = 0; m < 4; ++m)
                #pragma unroll
                for (int nn = 0; nn < 2; ++nn)
                    acc2[m][nn] = __builtin_amdgcn_mfma_f32_16x16x32_bf16(a[m], B2[nn * 4 + s], acc2[m][nn], 0, 0, 0);
        }
    }
    __syncthreads();

    float* sXf = (float*)sX;
    #pragma unroll
    for (int nn = 0; nn < 2; ++nn) {
        int outc = nbase + nn * 16 + lrow;
        float bb = be2[outc];
        #pragma unroll
        for (int m = 0; m < 4; ++m)
            #pragma unroll
            for (int r = 0; r < 4; ++r)
                sXf[(m * 16 + g4 + r) * SFS + outc] = silu_f(acc2[m][nn][r] + bb);
    }
    __syncthreads();

    {
        const int ct = t & 127;
        const int half = t >> 7;
        const int ebeg = half * 32, eend = ebeg + 32;
        float run = 0.f;
        int prev = srow[ebeg];
        for (int e = ebeg; e < eend; ++e) {
            int r = srow[e];
            if (r != prev) {
                if (run != 0.f) atomicAdd(&aggf[(size_t)prev * D + ct], run);
                run = 0.f; prev = r;
            }
            int eg = sEid[e];
            if (eg >= 0) {
                float v = sXf[e * SFS + ct];
                __builtin_nontemporal_store(v, &ef_out[(size_t)eg * D + ct]);
                run += v;
            }
        }
        if (run != 0.f) atomicAdd(&aggf[(size_t)prev * D + ct], run);
    }
}

// ---------------- node model (aliased LDS, 4 blocks/CU) ----------------
__global__ __launch_bounds__(256, 4) void node_kernel(
    const float* __restrict__ h, const float* __restrict__ aggf,
    const u16* __restrict__ agg16,
    const u16* __restrict__ wt,
    const float* __restrict__ bn1, const float* __restrict__ bn2,
    float* __restrict__ h_out, int N)
{
    __shared__ __align__(16) u16 uni[64 * SXS];   // 33792 B union: sX / sH1 / sXf
    u16* sX = uni;
    u16* sH1 = uni;
    float* sXf = (float*)uni;

    const int t = threadIdx.x;
    const int lane = t & 63;
    const int wid = t >> 6;
    const int n0 = blockIdx.x * 64;

    {
        const int e = t & 63;
        const int q = t >> 6;
        int ng = n0 + e; int ns = (ng < N) ? ng : N - 1;
        u16* dst = sX + e * SXS + q * 64;
        if (q >= 2 && agg16) {
            const u16* src = agg16 + (size_t)ns * D + (q & 1) * 64;
            #pragma unroll
            for (int i = 0; i < 8; ++i)
                *(uint4*)(dst + i * 8) = *(const uint4*)(src + i * 8);
        } else {
            const float4* src = (const float4*)(((q < 2) ? h : aggf) + (size_t)ns * D + (q & 1) * 64);
            #pragma unroll
            for (int i = 0; i < 8; ++i) {
                float4 a = src[2 * i], b = src[2 * i + 1];
                *(uint4*)(dst + i * 8) = make_uint4(cvt_pk_bf16(a.x, a.y), cvt_pk_bf16(a.z, a.w),
                                                   cvt_pk_bf16(b.x, b.y), cvt_pk_bf16(b.z, b.w));
            }
        }
    }
    __syncthreads();

    const int lrow = lane & 15;
    const int kg = lane >> 4;
    const int g4 = kg * 4;
    const int nbase = wid * 32;

    f32x4 acc[4][2] = {};
    {
        bf16x8 B1[16];
        #pragma unroll
        for (int nn = 0; nn < 2; ++nn)
            #pragma unroll
            for (int s = 0; s < 8; ++s)
                B1[nn * 8 + s] = *(const bf16x8*)(wt + 49152 + (size_t)(nbase + nn * 16 + lrow) * 256 + s * 32 + kg * 8);
        #pragma unroll
        for (int s = 0; s < 8; ++s) {
            bf16x8 a[4];
            #pragma unroll
            for (int m = 0; m < 4; ++m)
                a[m] = *(const bf16x8*)(sX + (m * 16 + lrow) * SXS + s * 32 + kg * 8);
            #pragma unroll
            for (int m = 0; m < 4; ++m)
                #pragma unroll
                for (int nn = 0; nn < 2; ++nn)
                    acc[m][nn] = __builtin_amdgcn_mfma_f32_16x16x32_bf16(a[m], B1[nn * 8 + s], acc[m][nn], 0, 0, 0);
        }
    }
    __syncthreads();   // sX dead before sH1 overwrite

    #pragma unroll
    for (int nn = 0; nn < 2; ++nn) {
        int outc = nbase + nn * 16 + lrow;
        float bb = bn1[outc];
        #pragma unroll
        for (int m = 0; m < 4; ++m)
            #pragma unroll
            for (int r = 0; r < 4; ++r)
                sH1[(m * 16 + g4 + r) * SHS + outc] = cvt1_bf16(silu_f(acc[m][nn][r] + bb));
    }
    __syncthreads();

    f32x4 acc2[4][2] = {};
    {
        bf16x8 B2[8];
        #pragma unroll
        for (int nn = 0; nn < 2; ++nn)
            #pragma unroll
            for (int s = 0; s < 4; ++s)
                B2[nn * 4 + s] = *(const bf16x8*)(wt + 81920 + (size_t)(nbase + nn * 16 + lrow) * 128 + s * 32 + kg * 8);
        #pragma unroll
        for (int s = 0; s < 4; ++s) {
            bf16x8 a[4];
            #pragma unroll
            for (int m = 0; m < 4; ++m)
                a[m] = *(const bf16x8*)(sH1 + (m * 16 + lrow) * SHS + s * 32 + kg * 8);
            #pragma unroll
            for (int m = 0; m < 4; ++m)
                #pragma unroll
                for (int nn = 0; nn < 2; ++nn)
                    acc2[m][nn] = __builtin_amdgcn_mfma_f32_16x16x32_bf16(a[m], B2[nn * 4 + s], acc2[m][nn], 0, 0, 0);
        }
    }
    __syncthreads();   // sH1 dead before sXf overwrite

    #pragma unroll
    for (int nn = 0; nn < 2; ++nn) {
        int outc = nbase + nn * 16 + lrow;
        float bb = bn2[outc];
        #pragma unroll
        for (int m = 0; m < 4; ++m)
            #pragma unroll
            for (int r = 0; r < 4; ++r)
                sXf[(m * 16 + g4 + r) * SFS + outc] = acc2[m][nn][r] + bb;
    }
    __syncthreads();

    {
        const int f4 = t & 31;
        const int nb = t >> 5;
        #pragma unroll
        for (int i = 0; i < 8; ++i) {
            int nl = nb + i * 8;
            int ng = n0 + nl;
            if (ng < N) {
                f32x4 v = *(const f32x4*)&sXf[nl * SFS + f4 * 4];
                const f32x4 hv = *(const f32x4*)&h[(size_t)ng * D + f4 * 4];
                v += hv;
                __builtin_nontemporal_store(v, (f32x4*)&h_out[(size_t)ng * D + f4 * 4]);
            }
        }
    }
}

extern "C" void kernel_launch(void* const* d_in, const int* in_sizes, int n_in,
                              void* d_out, int out_size, void* d_ws, size_t ws_size,
                              hipStream_t stream) {
    const float* h     = (const float*)d_in[0];
    const int*   ei    = (const int*)d_in[1];
    const float* coord = (const float*)d_in[2];
    const float* lbox  = (const float*)d_in[4];
    const float* We1   = (const float*)d_in[5];
    const float* be1   = (const float*)d_in[6];
    const float* We2   = (const float*)d_in[7];
    const float* be2   = (const float*)d_in[8];
    const float* Wn1   = (const float*)d_in[9];
    const float* bn1   = (const float*)d_in[10];
    const float* Wn2   = (const float*)d_in[11];
    const float* bn2   = (const float*)d_in[12];

    const int N = in_sizes[0] / D;
    const int E = in_sizes[1] / 2;

    float* out       = (float*)d_out;
    float* h_out     = out;                       // [N,128]
    float* coord_out = out + (size_t)N * D;       // [N,3]
    float* ef_out    = coord_out + (size_t)N * 3; // [E,128]
    float* aggf      = h_out;                     // f32 agg fallback (in-place)

    // workspace layout: wt | offs | cursor | bsum | perm | Pt | Qt | edata | agg16
    int* wsi = (int*)d_ws;
    u16* wt     = (u16*)d_ws;                     // 98304 u16 = 49152 ints
    int* offs   = wsi + 49152;                    // N+1 (padded N+8)
    int* cursor = offs + (N + 8);                 // N   (padded N+8)
    int* bsum   = cursor + (N + 8);               // 64
    int* perm   = bsum + 64;                      // E
    u16* Pt     = (u16*)(perm + E);               // N*128 bf16
    u16* Qt     = Pt + (size_t)N * D;             // N*128 bf16
    int4* edata = (int4*)(((uintptr_t)(Qt + (size_t)N * D) + 15) & ~(uintptr_t)15); // E int4
    u16* agg16  = (u16*)(edata + E);              // N*128 bf16

    size_t need_pq  = (size_t)((char*)(Qt + (size_t)N * D) - (char*)d_ws);
    size_t need_ed  = (size_t)((char*)(edata + E) - (char*)d_ws);
    size_t need_a16 = (size_t)((char*)(agg16 + (size_t)N * D) - (char*)d_ws);
    const bool use_pq  = ws_size >= need_pq;
    const bool use_ed  = use_pq && ws_size >= need_ed;
    const bool use_a16 = use_ed && ws_size >= need_a16;
    int4* edp  = use_ed ? edata : nullptr;
    u16*  a16p = use_a16 ? agg16 : nullptr;

    const int nb1 = (N + 1 + 1023) / 1024;        // scan1 blocks (<=64)

    prep_weights<<<384, 256, 0, stream>>>(We1, We2, Wn1, Wn2, wt);
    if (use_pq) {
        const int NBn = (N + 63) / 64;
        const int NBc = (N * 3 + 255) / 256;
        pq_kernel<<<NBn + NBc, 256, 0, stream>>>(h, wt, be1, Pt, Qt, cursor, N,
                                                 coord, lbox, coord_out, N * 3, NBn);
    } else {
        hipMemsetAsync(cursor, 0, (size_t)N * sizeof(int), stream);
        coord_kernel<<<(N * 3 + 255) / 256, 256, 0, stream>>>(coord, lbox, coord_out, N * 3);
    }

    // zero agg accumulator
    if (use_a16)
        hipMemsetAsync(agg16, 0, (size_t)N * D * sizeof(u16), stream);
    else
        hipMemsetAsync(aggf, 0, (size_t)N * D * sizeof(float), stream);

    // CSR build
    hist_kernel<<<(E + 255) / 256, 256, 0, stream>>>(ei, cursor, E);
    scan1_kernel<<<nb1, 256, 0, stream>>>(cursor, offs, bsum, N + 1);
    scan2_kernel<<<1, 64, 0, stream>>>(bsum, nb1);
    scan3_kernel<<<(N + 1 + 255) / 256, 256, 0, stream>>>(offs, bsum, cursor, N + 1);
    scatter_kernel<<<(E + 255) / 256, 256, 0, stream>>>(ei, cursor, perm, edp, E);

    if (use_pq)
        edge_pq_kernel<<<(E + 63) / 64, 256, 0, stream>>>(
            Pt, Qt, ei, perm, edp, coord, lbox, wt, We1, be2, ef_out, aggf, a16p, E);
    else
        edge_fb_kernel<<<(E + 63) / 64, 256, 0, stream>>>(
            h, ei, perm, coord, lbox, wt, We1, be1, be2, ef_out, aggf, E);

    node_kernel<<<(N + 63) / 64, 256, 0, stream>>>(
        h, aggf, a16p, wt, bn1, bn2, h_out, N);
}

// Round 14
// 241.725 us; speedup vs baseline: 1.2275x; 1.0091x over previous
//
#include <hip/hip_runtime.h>
#include <math.h>

#define D 128
#define SXS 264   // node/fallback sX stride (u16)
#define SHS 132   // activation stride (u16): 66 dwords == 2 mod 8 -> conflict-free epi
#define SFS 132   // f32 out-buffer stride (dwords), fallback path

typedef unsigned int u32;
typedef unsigned short u16;
typedef __attribute__((ext_vector_type(8))) short bf16x8;
typedef __attribute__((ext_vector_type(4))) float f32x4;
typedef __attribute__((ext_vector_type(2))) float f32x2;

__device__ __forceinline__ float bfl(u32 u) { return __uint_as_float(u << 16); }
__device__ __forceinline__ float bfh(u32 u) { return __uint_as_float(u & 0xFFFF0000u); }
__device__ __forceinline__ u16 f2bf(float f) {
    u32 u = __float_as_uint(f);
    return (u16)((u + 0x7FFFu + ((u >> 16) & 1u)) >> 16); // RNE (cold paths)
}
// HW packed f32->bf16 (RNE), 1 VALU op
__device__ __forceinline__ u32 cvt_pk_bf16(float lo, float hi) {
    u32 r;
    asm("v_cvt_pk_bf16_f32 %0, %1, %2" : "=v"(r) : "v"(lo), "v"(hi));
    return r;
}
__device__ __forceinline__ u16 cvt1_bf16(float v) { return (u16)cvt_pk_bf16(v, v); }
// fast SiLU: v_exp + v_rcp (1-ulp approx rcp — invisible at bf16 output precision)
__device__ __forceinline__ float silu_f(float x) {
    float e = __expf(-x);
    return x * __builtin_amdgcn_rcpf(1.0f + e);
}
// device-scope packed bf16 atomic add (gfx940+), no return
__device__ __forceinline__ void atomic_pk_add_bf16(u16* addr, u32 pk) {
    asm volatile("global_atomic_pk_add_bf16 %0, %1, off sc1"
                 :: "v"(addr), "v"(pk) : "memory");
}

// ---------------- coord: out = remainder(coord, l) (standalone, fallback path) ----------------
__global__ void coord_kernel(const float* __restrict__ coord,
                             const float* __restrict__ lbox,
                             float* __restrict__ out, int n3) {
    int i = blockIdx.x * 256 + threadIdx.x;
    if (i < n3) {
        float ld = lbox[i % 3];
        float c = coord[i];
        float r = fmodf(c, ld);
        if (r < 0.f) r += ld;
        out[i] = r;
    }
}

// ---------------- fused prep: weights->bf16T | zero cursor | zero agg16 | zero bstate ----------------
__global__ __launch_bounds__(256) void prep_plus_kernel(
    const float* __restrict__ We1, const float* __restrict__ We2,
    const float* __restrict__ Wn1, const float* __restrict__ Wn2,
    u16* __restrict__ wt,
    int* __restrict__ cursor, int N,
    u16* __restrict__ agg16, long agg_n,
    int* __restrict__ bstate,
    int B1, int B2, int B3)
{
    const int b = blockIdx.x, t = threadIdx.x;
    if (b < B1) {
        int i = b * 256 + t;
        if (i < 32768)        { int n = i >> 8, k = i & 255;              wt[i] = f2bf(We1[(size_t)k*D + n]); }
        else if (i < 49152)   { int j = i - 32768; int n = j >> 7, k = j & 127; wt[i] = f2bf(We2[(size_t)k*D + n]); }
        else if (i < 81920)   { int j = i - 49152; int n = j >> 8, k = j & 255; wt[i] = f2bf(Wn1[(size_t)k*D + n]); }
        else                  { int j = i - 81920; int n = j >> 7, k = j & 127; wt[i] = f2bf(Wn2[(size_t)k*D + n]); }
    } else if (b < B2) {
        int i = ((b - B1) * 256 + t) * 4;
        if (i + 3 < N) *(int4*)(cursor + i) = make_int4(0, 0, 0, 0);
        else for (int k = 0; k < 4; ++k) if (i + k < N) cursor[i + k] = 0;
    } else if (b < B3) {
        long i = ((long)(b - B2) * 256 + t) * 8;
        if (agg16 && i < agg_n) *(uint4*)(agg16 + i) = make_uint4(0, 0, 0, 0);
    } else {
        if (t < 64) bstate[t] = 0;
    }
}

// ---------------- CSR build (4 edges/thread) ----------------
__global__ void hist4_kernel(const int* __restrict__ ei, int* __restrict__ cnt, int E) {
    int i = (blockIdx.x * 256 + threadIdx.x) * 4;
    if (i + 3 < E) {
        int4 r = *(const int4*)(ei + i);
        atomicAdd(&cnt[r.x], 1); atomicAdd(&cnt[r.y], 1);
        atomicAdd(&cnt[r.z], 1); atomicAdd(&cnt[r.w], 1);
    } else {
        for (int k = 0; k < 4; ++k) if (i + k < E) atomicAdd(&cnt[ei[i + k]], 1);
    }
}

// single-dispatch exclusive scan with 64-lane lookback (requires gridDim.x <= 64, co-resident)
// in: cursor = counts; out: cursor = start positions
__global__ __launch_bounds__(256) void scan_lb_kernel(int* __restrict__ cursor,
                                                      int* __restrict__ bstate, int n) {
    __shared__ int s[256];
    __shared__ int sExcl;
    const int t = threadIdx.x, b = blockIdx.x;
    const int base = b * 1024 + t * 4;
    int v[4];
    #pragma unroll
    for (int i = 0; i < 4; ++i) { int idx = base + i; v[i] = (idx < n - 1) ? cursor[idx] : 0; }
    int lsum = v[0] + v[1] + v[2] + v[3];
    s[t] = lsum; __syncthreads();
    #pragma unroll
    for (int off = 1; off < 256; off <<= 1) {
        int x = (t >= off) ? s[t - off] : 0; __syncthreads();
        s[t] += x; __syncthreads();
    }
    if (t == 0)
        __hip_atomic_store(&bstate[b], 0x40000000 | s[255], __ATOMIC_RELEASE, __HIP_MEMORY_SCOPE_AGENT);
    if (t < 64) {
        int val = 0;
        if (t < b) {
            int st;
            do { st = __hip_atomic_load(&bstate[t], __ATOMIC_ACQUIRE, __HIP_MEMORY_SCOPE_AGENT); }
            while (!(st & 0x40000000));
            val = st & 0x3FFFFFFF;
        }
        #pragma unroll
        for (int off = 1; off < 64; off <<= 1) val += __shfl_xor(val, off, 64);
        if (t == 0) sExcl = val;
    }
    __syncthreads();
    int run = sExcl + s[t] - lsum;
    #pragma unroll
    for (int i = 0; i < 4; ++i) {
        int idx = base + i;
        if (idx < n - 1) cursor[idx] = run;
        run += v[i];
    }
}

// fallback 3-pass scan (if gridDim would exceed 64)
__global__ void scan1_kernel(const int* __restrict__ cnt, int* __restrict__ offs,
                             int* __restrict__ bsum, int n) {
    __shared__ int s[256];
    int t = threadIdx.x, b = blockIdx.x;
    int base = b * 1024 + t * 4;
    int v[4];
    #pragma unroll
    for (int i = 0; i < 4; ++i) { int idx = base + i; v[i] = (idx < n - 1) ? cnt[idx] : 0; }
    int lsum = v[0] + v[1] + v[2] + v[3];
    s[t] = lsum; __syncthreads();
    #pragma unroll
    for (int off = 1; off < 256; off <<= 1) {
        int x = (t >= off) ? s[t - off] : 0; __syncthreads();
        s[t] += x; __syncthreads();
    }
    int run = s[t] - lsum;
    #pragma unroll
    for (int i = 0; i < 4; ++i) { int idx = base + i; if (idx < n) offs[idx] = run; run += v[i]; }
    if (t == 255) bsum[b] = s[255];
}

__global__ void scan2_kernel(int* __restrict__ bsum, int nb) {
    __shared__ int s[64];
    int t = threadIdx.x;
    int orig = (t < nb) ? bsum[t] : 0;
    s[t] = orig; __syncthreads();
    #pragma unroll
    for (int off = 1; off < 64; off <<= 1) {
        int x = (t >= off) ? s[t - off] : 0; __syncthreads();
        s[t] += x; __syncthreads();
    }
    if (t < nb) bsum[t] = s[t] - orig;
}

__global__ void scan3_kernel(int* __restrict__ offs, const int* __restrict__ bsum,
                             int* __restrict__ cursor, int n) {
    int i = blockIdx.x * 256 + threadIdx.x;
    if (i < n) {
        int v = offs[i] + bsum[i >> 10];
        offs[i] = v;
        if (i < n - 1) cursor[i] = v;
    }
}

// scatter (4 edges/thread): writes either perm[p]=e or edata[p]={e,row,col,0}
__global__ void scatter4_kernel(const int* __restrict__ ei, int* __restrict__ cursor,
                                int* __restrict__ perm, int4* __restrict__ edata, int E) {
    int i = (blockIdx.x * 256 + threadIdx.x) * 4;
    if (i + 3 < E) {
        int4 r = *(const int4*)(ei + i);
        int4 c = *(const int4*)(ei + (size_t)E + i);
        int p0 = atomicAdd(&cursor[r.x], 1);
        int p1 = atomicAdd(&cursor[r.y], 1);
        int p2 = atomicAdd(&cursor[r.z], 1);
        int p3 = atomicAdd(&cursor[r.w], 1);
        if (edata) {
            edata[p0] = make_int4(i,     r.x, c.x, 0);
            edata[p1] = make_int4(i + 1, r.y, c.y, 0);
            edata[p2] = make_int4(i + 2, r.z, c.z, 0);
            edata[p3] = make_int4(i + 3, r.w, c.w, 0);
        } else {
            perm[p0] = i; perm[p1] = i + 1; perm[p2] = i + 2; perm[p3] = i + 3;
        }
    } else {
        for (int k = 0; k < 4; ++k) {
            int e = i + k;
            if (e < E) {
                int r = ei[e], c = ei[(size_t)E + e];
                int p = atomicAdd(&cursor[r], 1);
                if (edata) edata[p] = make_int4(e, r, c, 0);
                else perm[p] = e;
            }
        }
    }
}

// ---------------- P/Q precompute (+ coord tail blocks): P = h@W_top + be1, Q = h@W_mid ----------------
__global__ __launch_bounds__(256, 4) void pq_kernel(
    const float* __restrict__ h, const u16* __restrict__ wt,
    const float* __restrict__ be1,
    u16* __restrict__ Pt, u16* __restrict__ Qt, int N,
    const float* __restrict__ coord, const float* __restrict__ lbox,
    float* __restrict__ coord_out, int n3, int NBn)
{
    __shared__ __align__(16) u16 sA[64 * SHS];
    __shared__ __align__(16) u16 sO[64 * SHS];

    const int t = threadIdx.x;

    // tail blocks: coord remainder
    if (blockIdx.x >= NBn) {
        int i = (blockIdx.x - NBn) * 256 + t;
        if (i < n3) {
            float ld = lbox[i % 3];
            float c = coord[i];
            float r = fmodf(c, ld);
            if (r < 0.f) r += ld;
            coord_out[i] = r;
        }
        return;
    }

    const int lane = t & 63;
    const int wid = t >> 6;
    const int n0 = blockIdx.x * 64;

    // stage h (f32 -> bf16) [64][128]
    {
        const int e = t & 63, q = t >> 6;
        int ng = n0 + e; int ns = (ng < N) ? ng : N - 1;
        const float4* src = (const float4*)(h + (size_t)ns * D + q * 32);
        u16* dst = sA + e * SHS + q * 32;
        #pragma unroll
        for (int c = 0; c < 4; ++c) {
            float4 a = src[2 * c], b = src[2 * c + 1];
            *(uint4*)(dst + c * 8) = make_uint4(cvt_pk_bf16(a.x, a.y), cvt_pk_bf16(a.z, a.w),
                                               cvt_pk_bf16(b.x, b.y), cvt_pk_bf16(b.z, b.w));
        }
    }
    __syncthreads();

    const int lrow = lane & 15;
    const int kg = lane >> 4;
    const int g4 = kg * 4;
    const int nbase = wid * 32;

    f32x4 accP[4][2] = {}, accQ[4][2] = {};
    {
        bf16x8 Bt[8], Bm[8];
        #pragma unroll
        for (int nn = 0; nn < 2; ++nn)
            #pragma unroll
            for (int s = 0; s < 4; ++s) {
                const u16* bp = wt + (size_t)(nbase + nn * 16 + lrow) * 256 + s * 32 + kg * 8;
                Bt[nn * 4 + s] = *(const bf16x8*)bp;
                Bm[nn * 4 + s] = *(const bf16x8*)(bp + 128);
            }
        #pragma unroll
        for (int s = 0; s < 4; ++s) {
            bf16x8 a[4];
            #pragma unroll
            for (int m = 0; m < 4; ++m)
                a[m] = *(const bf16x8*)(sA + (m * 16 + lrow) * SHS + s * 32 + kg * 8);
            #pragma unroll
            for (int m = 0; m < 4; ++m)
                #pragma unroll
                for (int nn = 0; nn < 2; ++nn) {
                    accP[m][nn] = __builtin_amdgcn_mfma_f32_16x16x32_bf16(a[m], Bt[nn * 4 + s], accP[m][nn], 0, 0, 0);
                    accQ[m][nn] = __builtin_amdgcn_mfma_f32_16x16x32_bf16(a[m], Bm[nn * 4 + s], accQ[m][nn], 0, 0, 0);
                }
        }
    }

    // --- P: +be1, pack bf16, coalesced copy-out ---
    #pragma unroll
    for (int nn = 0; nn < 2; ++nn) {
        int outc = nbase + nn * 16 + lrow;
        float bb = be1[outc];
        #pragma unroll
        for (int m = 0; m < 4; ++m)
            #pragma unroll
            for (int r = 0; r < 4; ++r)
                sO[(m * 16 + g4 + r) * SHS + outc] = cvt1_bf16(accP[m][nn][r] + bb);
    }
    __syncthreads();
    {
        const int f4 = t & 15, rb = t >> 4;
        #pragma unroll
        for (int p = 0; p < 4; ++p) {
            int row = rb + p * 16;
            int ng = n0 + row;
            if (ng < N)
                *(uint4*)(Pt + (size_t)ng * D + f4 * 8) = *(const uint4*)(sO + row * SHS + f4 * 8);
        }
    }
    __syncthreads();
    // --- Q ---
    #pragma unroll
    for (int nn = 0; nn < 2; ++nn) {
        int outc = nbase + nn * 16 + lrow;
        #pragma unroll
        for (int m = 0; m < 4; ++m)
            #pragma unroll
            for (int r = 0; r < 4; ++r)
                sO[(m * 16 + g4 + r) * SHS + outc] = cvt1_bf16(accQ[m][nn][r]);
    }
    __syncthreads();
    {
        const int f4 = t & 15, rb = t >> 4;
        #pragma unroll
        for (int p = 0; p < 4; ++p) {
            int row = rb + p * 16;
            int ng = n0 + row;
            if (ng < N)
                *(uint4*)(Qt + (size_t)ng * D + f4 * 8) = *(const uint4*)(sO + row * SHS + f4 * 8);
        }
    }
}

// ---------------- edge model (P/Q path; bf16 LDS union; 8 blocks/CU) ----------------
__global__ __launch_bounds__(256, 8) void edge_pq_kernel(
    const u16* __restrict__ Pt, const u16* __restrict__ Qt,
    const int* __restrict__ ei, const int* __restrict__ perm,
    const int4* __restrict__ edata,
    const float* __restrict__ coord, const float* __restrict__ lbox,
    const u16* __restrict__ wt, const float* __restrict__ We1,
    const float* __restrict__ be2,
    float* __restrict__ ef_out, float* __restrict__ aggf,
    u16* __restrict__ agg16, int E)
{
    __shared__ __align__(16) u16 uni[64 * SHS];   // 16896 B union: sH1 / sE16
    __shared__ int srow[64], scol[64], sEid[64];
    __shared__ float sRad[64];
    __shared__ float sW[128];
    u16* sH1 = uni;
    u16* sE16 = uni;

    const int t = threadIdx.x;
    const int lane = t & 63;
    const int wid = t >> 6;

    // bijective XCD swizzle (m204)
    int p0;
    {
        const int nwg = gridDim.x;
        const int orig = blockIdx.x;
        const int q = nwg >> 3, r = nwg & 7;
        const int xcd = orig & 7, idx = orig >> 3;
        const int tile = (xcd < r ? xcd * (q + 1) : r * (q + 1) + (xcd - r) * q) + idx;
        p0 = tile * 64;
    }

    if (t < 64) {
        int slot = p0 + t;
        bool valid = slot < E;
        int cs = valid ? slot : (E - 1);
        int eg, rr, cc;
        if (edata) {
            int4 ed = edata[cs];
            eg = ed.x; rr = ed.y; cc = ed.z;
        } else {
            eg = perm[cs];
            rr = ei[eg];
            cc = ei[(size_t)E + eg];
        }
        sEid[t] = valid ? eg : -1;
        srow[t] = rr;
        scol[t] = cc;
        float rad = 0.f;
        #pragma unroll
        for (int d3 = 0; d3 < 3; ++d3) {
            float df = coord[(size_t)rr * 3 + d3] - coord[(size_t)cc * 3 + d3];
            float ld = lbox[d3];
            df = (df >  0.5f * ld) ? df - ld : df;
            df = (df < -0.5f * ld) ? df + ld : df;
            rad += df * df;
        }
        sRad[t] = rad;
    } else if (t < 192) {
        sW[t - 64] = We1[(size_t)256 * D + (t - 64)];   // radial row of We1
    }
    __syncthreads();

    // phase 1: gather P[row]+Q[col], + rad*w, SiLU -> sH1 bf16
    {
        const int e = t & 63, q = t >> 6;
        const u16* Pp = Pt + (size_t)srow[e] * D;
        const u16* Qp = Qt + (size_t)scol[e] * D;
        const float rad = sRad[e];
        #pragma unroll
        for (int c0 = 0; c0 < 4; ++c0) {
            int j0 = q * 32 + c0 * 8;
            uint4 pu = *(const uint4*)(Pp + j0);
            uint4 qu = *(const uint4*)(Qp + j0);
            u32 pa[4] = {pu.x, pu.y, pu.z, pu.w};
            u32 qa[4] = {qu.x, qu.y, qu.z, qu.w};
            u32 ow[4];
            #pragma unroll
            for (int k = 0; k < 4; ++k) {
                float w0 = sW[j0 + 2 * k], w1 = sW[j0 + 2 * k + 1];
                float v0 = silu_f(bfl(pa[k]) + bfl(qa[k]) + rad * w0);
                float v1 = silu_f(bfh(pa[k]) + bfh(qa[k]) + rad * w1);
                ow[k] = cvt_pk_bf16(v0, v1);
            }
            *(uint4*)(sH1 + e * SHS + j0) = make_uint4(ow[0], ow[1], ow[2], ow[3]);
        }
    }
    __syncthreads();

    const int lrow = lane & 15;
    const int kg = lane >> 4;
    const int g4 = kg * 4;
    const int nbase = wid * 32;

    // phase 2: GEMM2 (K=128)
    f32x4 acc2[4][2] = {};
    {
        bf16x8 B2[8];
        #pragma unroll
        for (int nn = 0; nn < 2; ++nn)
            #pragma unroll
            for (int s = 0; s < 4; ++s)
                B2[nn * 4 + s] = *(const bf16x8*)(wt + 32768 + (size_t)(nbase + nn * 16 + lrow) * 128 + s * 32 + kg * 8);
        #pragma unroll
        for (int s = 0; s < 4; ++s) {
            bf16x8 a[4];
            #pragma unroll
            for (int m = 0; m < 4; ++m)
                a[m] = *(const bf16x8*)(sH1 + (m * 16 + lrow) * SHS + s * 32 + kg * 8);
            #pragma unroll
            for (int m = 0; m < 4; ++m)
                #pragma unroll
                for (int nn = 0; nn < 2; ++nn)
                    acc2[m][nn] = __builtin_amdgcn_mfma_f32_16x16x32_bf16(a[m], B2[nn * 4 + s], acc2[m][nn], 0, 0, 0);
        }
    }
    __syncthreads();   // sH1 dead before sE16 overwrite

    // phase 3: bias + SiLU -> bf16 buffer (same union)
    #pragma unroll
    for (int nn = 0; nn < 2; ++nn) {
        int outc = nbase + nn * 16 + lrow;
        float bb = be2[outc];
        #pragma unroll
        for (int m = 0; m < 4; ++m)
            #pragma unroll
            for (int r = 0; r < 4; ++r)
                sE16[(m * 16 + g4 + r) * SHS + outc] = cvt1_bf16(silu_f(acc2[m][nn][r] + bb));
    }
    __syncthreads();

    // phase 4: merged ef write (NT) + segmented reduce
    if (agg16) {
        const int cp = t & 63;
        const int g = t >> 6;
        const int ebeg = g * 16, eend = ebeg + 16;
        float r0 = 0.f, r1 = 0.f;
        int prev = srow[ebeg];
        for (int e = ebeg; e < eend; ++e) {
            int r = srow[e];
            if (r != prev) {
                if (r0 != 0.f || r1 != 0.f)
                    atomic_pk_add_bf16(agg16 + (size_t)prev * D + 2 * cp, cvt_pk_bf16(r0, r1));
                r0 = 0.f; r1 = 0.f; prev = r;
            }
            int eg = sEid[e];
            if (eg >= 0) {
                u32 pk2 = *(const u32*)(sE16 + e * SHS + 2 * cp);
                float v0 = bfl(pk2), v1 = bfh(pk2);
                f32x2 vv = {v0, v1};
                __builtin_nontemporal_store(vv, (f32x2*)&ef_out[(size_t)eg * D + 2 * cp]);
                r0 += v0; r1 += v1;
            }
        }
        if (r0 != 0.f || r1 != 0.f)
            atomic_pk_add_bf16(agg16 + (size_t)prev * D + 2 * cp, cvt_pk_bf16(r0, r1));
    } else {
        const int ct = t & 127;
        const int half = t >> 7;
        const int ebeg = half * 32, eend = ebeg + 32;
        float run = 0.f;
        int prev = srow[ebeg];
        for (int e = ebeg; e < eend; ++e) {
            int r = srow[e];
            if (r != prev) {
                if (run != 0.f) atomicAdd(&aggf[(size_t)prev * D + ct], run);
                run = 0.f; prev = r;
            }
            int eg = sEid[e];
            if (eg >= 0) {
                float v = __uint_as_float((u32)sE16[e * SHS + ct] << 16);
                __builtin_nontemporal_store(v, &ef_out[(size_t)eg * D + ct]);
                run += v;
            }
        }
        if (run != 0.f) atomicAdd(&aggf[(size_t)prev * D + ct], run);
    }
}

// ---------------- edge fallback (f32 staging, own GEMM1) ----------------
__global__ __launch_bounds__(256, 3) void edge_fb_kernel(
    const float* __restrict__ h,
    const int* __restrict__ ei, const int* __restrict__ perm,
    const float* __restrict__ coord, const float* __restrict__ lbox,
    const u16* __restrict__ wt,
    const float* __restrict__ We1, const float* __restrict__ be1,
    const float* __restrict__ be2,
    float* __restrict__ ef_out, float* __restrict__ aggf, int E)
{
    __shared__ __align__(16) u16 sX[64 * SXS];
    __shared__ __align__(16) u16 sH1[64 * SHS];
    __shared__ int srow[64], scol[64], sEid[64];
    __shared__ float sRad[64];

    const int t = threadIdx.x;
    const int lane = t & 63;
    const int wid = t >> 6;

    int p0;
    {
        const int nwg = gridDim.x;
        const int orig = blockIdx.x;
        const int q = nwg >> 3, r = nwg & 7;
        const int xcd = orig & 7, idx = orig >> 3;
        const int tile = (xcd < r ? xcd * (q + 1) : r * (q + 1) + (xcd - r) * q) + idx;
        p0 = tile * 64;
    }

    if (t < 64) {
        int slot = p0 + t;
        int eg = perm[(slot < E) ? slot : (E - 1)];
        sEid[t] = (p0 + t < E) ? eg : -1;
        srow[t] = ei[eg];
        scol[t] = ei[(size_t)E + eg];
    }
    __syncthreads();

    {
        const int e = t & 63;
        const int q = t >> 6;
        const int r = srow[e], c = scol[e];
        const float4* src = (const float4*)((q < 2) ? (h + (size_t)r * D + (q & 1) * 64)
                                                    : (h + (size_t)c * D + (q & 1) * 64));
        u16* dst = sX + e * SXS + q * 64;
        #pragma unroll
        for (int i = 0; i < 8; ++i) {
            float4 a = src[2 * i], b = src[2 * i + 1];
            *(uint4*)(dst + i * 8) = make_uint4(cvt_pk_bf16(a.x, a.y), cvt_pk_bf16(a.z, a.w),
                                               cvt_pk_bf16(b.x, b.y), cvt_pk_bf16(b.z, b.w));
        }
        if (t < 64) {
            int rr = srow[t], cc = scol[t];
            float rad = 0.f;
            #pragma unroll
            for (int d3 = 0; d3 < 3; ++d3) {
                float df = coord[(size_t)rr * 3 + d3] - coord[(size_t)cc * 3 + d3];
                float ld = lbox[d3];
                df = (df >  0.5f * ld) ? df - ld : df;
                df = (df < -0.5f * ld) ? df + ld : df;
                rad += df * df;
            }
            sRad[t] = rad;
        }
    }
    __syncthreads();

    const int lrow = lane & 15;
    const int kg = lane >> 4;
    const int g4 = kg * 4;
    const int nbase = wid * 32;

    f32x4 acc[4][2] = {};
    {
        bf16x8 B1[16];
        #pragma unroll
        for (int nn = 0; nn < 2; ++nn)
            #pragma unroll
            for (int s = 0; s < 8; ++s)
                B1[nn * 8 + s] = *(const bf16x8*)(wt + (size_t)(nbase + nn * 16 + lrow) * 256 + s * 32 + kg * 8);
        #pragma unroll
        for (int s = 0; s < 8; ++s) {
            bf16x8 a[4];
            #pragma unroll
            for (int m = 0; m < 4; ++m)
                a[m] = *(const bf16x8*)(sX + (m * 16 + lrow) * SXS + s * 32 + kg * 8);
            #pragma unroll
            for (int m = 0; m < 4; ++m)
                #pragma unroll
                for (int nn = 0; nn < 2; ++nn)
                    acc[m][nn] = __builtin_amdgcn_mfma_f32_16x16x32_bf16(a[m], B1[nn * 8 + s], acc[m][nn], 0, 0, 0);
        }
    }

    #pragma unroll
    for (int nn = 0; nn < 2; ++nn) {
        int outc = nbase + nn * 16 + lrow;
        float wl = We1[(size_t)256 * D + outc];
        float bb = be1[outc];
        #pragma unroll
        for (int m = 0; m < 4; ++m)
            #pragma unroll
            for (int r = 0; r < 4; ++r) {
                int e = m * 16 + g4 + r;
                float v = acc[m][nn][r] + sRad[e] * wl + bb;
                sH1[e * SHS + outc] = cvt1_bf16(silu_f(v));
            }
    }
    __syncthreads();

    f32x4 acc2[4][2] = {};
    {
        bf16x8 B2[8];
        #pragma unroll
        for (int nn = 0; nn < 2; ++nn)
            #pragma unroll
            for (int s = 0; s < 4; ++s)
                B2[nn * 4 + s] = *(const bf16x8*)(wt + 32768 + (size_t)(nbase + nn * 16 + lrow) * 128 + s * 32 + kg * 8);
        #pragma unroll
        for (int s = 0; s < 4; ++s) {
            bf16x8 a[4];
            #pragma unroll
            for (int m = 0; m < 4; ++m)
                a[m] = *(const bf16x8*)(sH1 + (m * 16 + lrow) * SHS + s * 32 + kg * 8);
            #pragma unroll
            for (int m = 0; m < 4; ++m)
                #pragma unroll
                for (int nn = 0; nn < 2; ++nn)
                    acc2[m][nn] = __builtin_amdgcn_mfma_f32_16x16x32_bf16(a[m], B2[nn * 4 + s], acc2[m][nn], 0, 0, 0);
        }
    }
    __syncthreads();

    float* sXf = (float*)sX;
    #pragma unroll
    for (int nn = 0; nn < 2; ++nn) {
        int outc = nbase + nn * 16 + lrow;
        float bb = be2[outc];
        #pragma unroll
        for (int m = 0; m < 4; ++m)
            #pragma unroll
            for (int r = 0; r < 4; ++r)
                sXf[(m * 16 + g4 + r) * SFS + outc] = silu_f(acc2[m][nn][r] + bb);
    }
    __syncthreads();

    {
        const int ct = t & 127;
        const int half = t >> 7;
        const int ebeg = half * 32, eend = ebeg + 32;
        float run = 0.f;
        int prev = srow[ebeg];
        for (int e = ebeg; e < eend; ++e) {
            int r = srow[e];
            if (r != prev) {
                if (run != 0.f) atomicAdd(&aggf[(size_t)prev * D + ct], run);
                run = 0.f; prev = r;
            }
            int eg = sEid[e];
            if (eg >= 0) {
                float v = sXf[e * SFS + ct];
                __builtin_nontemporal_store(v, &ef_out[(size_t)eg * D + ct]);
                run += v;
            }
        }
        if (run != 0.f) atomicAdd(&aggf[(size_t)prev * D + ct], run);
    }
}

// ---------------- node model (aliased LDS, 4 blocks/CU) ----------------
__global__ __launch_bounds__(256, 4) void node_kernel(
    const float* __restrict__ h, const float* __restrict__ aggf,
    const u16* __restrict__ agg16,
    const u16* __restrict__ wt,
    const float* __restrict__ bn1, const float* __restrict__ bn2,
    float* __restrict__ h_out, int N)
{
    __shared__ __align__(16) u16 uni[64 * SXS];   // 33792 B union: sX / sH1 / sXf
    u16* sX = uni;
    u16* sH1 = uni;
    float* sXf = (float*)uni;

    const int t = threadIdx.x;
    const int lane = t & 63;
    const int wid = t >> 6;
    const int n0 = blockIdx.x * 64;

    {
        const int e = t & 63;
        const int q = t >> 6;
        int ng = n0 + e; int ns = (ng < N) ? ng : N - 1;
        u16* dst = sX + e * SXS + q * 64;
        if (q >= 2 && agg16) {
            const u16* src = agg16 + (size_t)ns * D + (q & 1) * 64;
            #pragma unroll
            for (int i = 0; i < 8; ++i)
                *(uint4*)(dst + i * 8) = *(const uint4*)(src + i * 8);
        } else {
            const float4* src = (const float4*)(((q < 2) ? h : aggf) + (size_t)ns * D + (q & 1) * 64);
            #pragma unroll
            for (int i = 0; i < 8; ++i) {
                float4 a = src[2 * i], b = src[2 * i + 1];
                *(uint4*)(dst + i * 8) = make_uint4(cvt_pk_bf16(a.x, a.y), cvt_pk_bf16(a.z, a.w),
                                                   cvt_pk_bf16(b.x, b.y), cvt_pk_bf16(b.z, b.w));
            }
        }
    }
    __syncthreads();

    const int lrow = lane & 15;
    const int kg = lane >> 4;
    const int g4 = kg * 4;
    const int nbase = wid * 32;

    f32x4 acc[4][2] = {};
    {
        bf16x8 B1[16];
        #pragma unroll
        for (int nn = 0; nn < 2; ++nn)
            #pragma unroll
            for (int s = 0; s < 8; ++s)
                B1[nn * 8 + s] = *(const bf16x8*)(wt + 49152 + (size_t)(nbase + nn * 16 + lrow) * 256 + s * 32 + kg * 8);
        #pragma unroll
        for (int s = 0; s < 8; ++s) {
            bf16x8 a[4];
            #pragma unroll
            for (int m = 0; m < 4; ++m)
                a[m] = *(const bf16x8*)(sX + (m * 16 + lrow) * SXS + s * 32 + kg * 8);
            #pragma unroll
            for (int m = 0; m < 4; ++m)
                #pragma unroll
                for (int nn = 0; nn < 2; ++nn)
                    acc[m][nn] = __builtin_amdgcn_mfma_f32_16x16x32_bf16(a[m], B1[nn * 8 + s], acc[m][nn], 0, 0, 0);
        }
    }
    __syncthreads();   // sX dead before sH1 overwrite

    #pragma unroll
    for (int nn = 0; nn < 2; ++nn) {
        int outc = nbase + nn * 16 + lrow;
        float bb = bn1[outc];
        #pragma unroll
        for (int m = 0; m < 4; ++m)
            #pragma unroll
            for (int r = 0; r < 4; ++r)
                sH1[(m * 16 + g4 + r) * SHS + outc] = cvt1_bf16(silu_f(acc[m][nn][r] + bb));
    }
    __syncthreads();

    f32x4 acc2[4][2] = {};
    {
        bf16x8 B2[8];
        #pragma unroll
        for (int nn = 0; nn < 2; ++nn)
            #pragma unroll
            for (int s = 0; s < 4; ++s)
                B2[nn * 4 + s] = *(const bf16x8*)(wt + 81920 + (size_t)(nbase + nn * 16 + lrow) * 128 + s * 32 + kg * 8);
        #pragma unroll
        for (int s = 0; s < 4; ++s) {
            bf16x8 a[4];
            #pragma unroll
            for (int m = 0; m < 4; ++m)
                a[m] = *(const bf16x8*)(sH1 + (m * 16 + lrow) * SHS + s * 32 + kg * 8);
            #pragma unroll
            for (int m = 0; m < 4; ++m)
                #pragma unroll
                for (int nn = 0; nn < 2; ++nn)
                    acc2[m][nn] = __builtin_amdgcn_mfma_f32_16x16x32_bf16(a[m], B2[nn * 4 + s], acc2[m][nn], 0, 0, 0);
        }
    }
    __syncthreads();   // sH1 dead before sXf overwrite

    #pragma unroll
    for (int nn = 0; nn < 2; ++nn) {
        int outc = nbase + nn * 16 + lrow;
        float bb = bn2[outc];
        #pragma unroll
        for (int m = 0; m < 4; ++m)
            #pragma unroll
            for (int r = 0; r < 4; ++r)
                sXf[(m * 16 + g4 + r) * SFS + outc] = acc2[m][nn][r] + bb;
    }
    __syncthreads();

    {
        const int f4 = t & 31;
        const int nb = t >> 5;
        #pragma unroll
        for (int i = 0; i < 8; ++i) {
            int nl = nb + i * 8;
            int ng = n0 + nl;
            if (ng < N) {
                f32x4 v = *(const f32x4*)&sXf[nl * SFS + f4 * 4];
                const f32x4 hv = *(const f32x4*)&h[(size_t)ng * D + f4 * 4];
                v += hv;
                __builtin_nontemporal_store(v, (f32x4*)&h_out[(size_t)ng * D + f4 * 4]);
            }
        }
    }
}

extern "C" void kernel_launch(void* const* d_in, const int* in_sizes, int n_in,
                              void* d_out, int out_size, void* d_ws, size_t ws_size,
                              hipStream_t stream) {
    const float* h     = (const float*)d_in[0];
    const int*   ei    = (const int*)d_in[1];
    const float* coord = (const float*)d_in[2];
    const float* lbox  = (const float*)d_in[4];
    const float* We1   = (const float*)d_in[5];
    const float* be1   = (const float*)d_in[6];
    const float* We2   = (const float*)d_in[7];
    const float* be2   = (const float*)d_in[8];
    const float* Wn1   = (const float*)d_in[9];
    const float* bn1   = (const float*)d_in[10];
    const float* Wn2   = (const float*)d_in[11];
    const float* bn2   = (const float*)d_in[12];

    const int N = in_sizes[0] / D;
    const int E = in_sizes[1] / 2;

    float* out       = (float*)d_out;
    float* h_out     = out;                       // [N,128]
    float* coord_out = out + (size_t)N * D;       // [N,3]
    float* ef_out    = coord_out + (size_t)N * 3; // [E,128]
    float* aggf      = h_out;                     // f32 agg fallback (in-place)

    // workspace layout: wt | offs | cursor | bsum | perm | Pt | Qt | edata | agg16
    int* wsi = (int*)d_ws;
    u16* wt     = (u16*)d_ws;                     // 98304 u16 = 49152 ints
    int* offs   = wsi + 49152;                    // N+1 (padded N+8) — fallback scan only
    int* cursor = offs + (N + 8);                 // N   (padded N+8)
    int* bsum   = cursor + (N + 8);               // 64 (doubles as bstate for lookback scan)
    int* perm   = bsum + 64;                      // E
    u16* Pt     = (u16*)(perm + E);               // N*128 bf16
    u16* Qt     = Pt + (size_t)N * D;             // N*128 bf16
    int4* edata = (int4*)(((uintptr_t)(Qt + (size_t)N * D) + 15) & ~(uintptr_t)15); // E int4
    u16* agg16  = (u16*)(edata + E);              // N*128 bf16

    size_t need_pq  = (size_t)((char*)(Qt + (size_t)N * D) - (char*)d_ws);
    size_t need_ed  = (size_t)((char*)(edata + E) - (char*)d_ws);
    size_t need_a16 = (size_t)((char*)(agg16 + (size_t)N * D) - (char*)d_ws);
    const bool use_pq  = ws_size >= need_pq;
    const bool use_ed  = use_pq && ws_size >= need_ed;
    const bool use_a16 = use_ed && ws_size >= need_a16;
    int4* edp  = use_ed ? edata : nullptr;
    u16*  a16p = use_a16 ? agg16 : nullptr;

    const int nb1 = (N + 1 + 1023) / 1024;        // scan blocks
    const bool lbscan = nb1 <= 64;                // lookback scan requires co-resident grid

    // fused prep: weights | zero cursor | zero agg16 | zero bstate
    const long agg_n = (long)N * D;               // u16 elements
    const int B1 = 384;
    const int B2 = B1 + (N / 4 + 255) / 256;
    const int B3 = B2 + (use_a16 ? (int)((agg_n / 8 + 255) / 256) : 0);
    const int Bt = B3 + 1;
    prep_plus_kernel<<<Bt, 256, 0, stream>>>(We1, We2, Wn1, Wn2, wt,
                                             cursor, N, a16p, agg_n, bsum, B1, B2, B3);

    if (use_pq) {
        const int NBn = (N + 63) / 64;
        const int NBc = (N * 3 + 255) / 256;
        pq_kernel<<<NBn + NBc, 256, 0, stream>>>(h, wt, be1, Pt, Qt, N,
                                                 coord, lbox, coord_out, N * 3, NBn);
    } else {
        coord_kernel<<<(N * 3 + 255) / 256, 256, 0, stream>>>(coord, lbox, coord_out, N * 3);
    }

    if (!use_a16)
        hipMemsetAsync(aggf, 0, (size_t)N * D * sizeof(float), stream);

    // CSR build
    hist4_kernel<<<(E / 4 + 255) / 256, 256, 0, stream>>>(ei, cursor, E);
    if (lbscan) {
        scan_lb_kernel<<<nb1, 256, 0, stream>>>(cursor, bsum, N + 1);
    } else {
        scan1_kernel<<<nb1, 256, 0, stream>>>(cursor, offs, bsum, N + 1);
        scan2_kernel<<<1, 64, 0, stream>>>(bsum, nb1);
        scan3_kernel<<<(N + 1 + 255) / 256, 256, 0, stream>>>(offs, bsum, cursor, N + 1);
    }
    scatter4_kernel<<<(E / 4 + 255) / 256, 256, 0, stream>>>(ei, cursor, perm, edp, E);

    if (use_pq)
        edge_pq_kernel<<<(E + 63) / 64, 256, 0, stream>>>(
            Pt, Qt, ei, perm, edp, coord, lbox, wt, We1, be2, ef_out, aggf, a16p, E);
    else
        edge_fb_kernel<<<(E + 63) / 64, 256, 0, stream>>>(
            h, ei, perm, coord, lbox, wt, We1, be1, be2, ef_out, aggf, E);

    node_kernel<<<(N + 63) / 64, 256, 0, stream>>>(
        h, aggf, a16p, wt, bn1, bn2, h_out, N);
}